// Round 1
// baseline (4959.192 us; speedup 1.0000x reference)
//
#include <hip/hip_runtime.h>
#include <math.h>

// Problem constants
#define B_     8
#define S_     4
#define H_     50
#define NH_    200
#define EHH_   400
#define L_     2
#define HID_   128
#define FDIM_  79          // 44 + 20 + 15
#define EDIM_  161         // 2*FDIM + 3
#define NN_    250         // H + NH
#define NE_    10400       // EHH + H*NH
#define BS_    32          // B*S
#define TOTE_  (BS_*NE_)   // 332800
#define FS_    80          // feat row stride (pad 79 -> 80)
#define TE_    32          // edges per block in edge kernel

// Workspace layout (float offsets)
#define OFF_FEAT   0                         // BS*NN*FS = 640000
#define OFF_X      640000                    // BS*NN*4  = 32000
#define OFF_X0H    672000                    // BS*H*4   = 6400
#define OFF_EROW   678400                    // B*NE (int) = 83200
#define OFF_ECOL   761600                    // 83200
#define OFF_EMASK  844800                    // 83200
#define OFF_EBOND  928000                    // 83200
#define OFF_AGGX   1011200                   // BS*H*4   = 6400
#define OFF_AGGM   1017600                   // BS*H*HID = 204800
#define OFF_HIW1   1222400                   // BS*H*HID = 204800
#define OFF_HJW1   1427200                   // BS*NN*HID = 1024000
// total = 2451200 floats = 9.8 MB

__device__ __forceinline__ float silu_(float v) {
    return v * (1.0f / (1.0f + __expf(-v)));
}

// ---------------- setup kernels ----------------

__global__ void k_embed(const int* __restrict__ lab_h, const int* __restrict__ pos_h,
                        const int* __restrict__ lab_hv, const int* __restrict__ pos_hv,
                        const int* __restrict__ pep, float* __restrict__ feat)
{
    int g = blockIdx.x * blockDim.x + threadIdx.x;
    if (g >= B_ * NN_) return;
    int b = g / NN_, n = g % NN_;
    int label, pos;
    if (n < H_) { label = lab_h[b*H_ + n];        pos = pos_h[b*H_ + n]; }
    else        { int nh = n - H_; label = lab_hv[b*NH_ + nh]; pos = pos_hv[b*NH_ + nh]; }
    int aa = pep[b*15 + (pos - 1)];
    for (int f = 0; f < FDIM_; ++f) {
        float v;
        if (f < 44)      v = (f == label)        ? 1.0f : 0.0f;
        else if (f < 64) v = ((f - 44) == aa)     ? 1.0f : 0.0f;
        else             v = ((f - 64) == pos - 1)? 1.0f : 0.0f;
        for (int s = 0; s < S_; ++s)
            feat[(((b*S_ + s)*NN_) + n)*FS_ + f] = v;
    }
}

__global__ void k_xinit(const float* __restrict__ x_h, const float* __restrict__ x_hv,
                        const int* __restrict__ bound, float* __restrict__ x,
                        float* __restrict__ x0h)
{
    int g = blockIdx.x * blockDim.x + threadIdx.x;
    if (g >= BS_ * NN_) return;
    int bs = g / NN_, n = g % NN_;
    int b = bs / S_;
    if (n < H_) {
        int ba = bound[b*H_ + n];
        for (int d = 0; d < 3; ++d) {
            float v = x_h[(bs*H_ + n)*3 + d] + x_hv[(b*NH_ + ba)*3 + d];
            x[g*4 + d] = v;
            x0h[(bs*H_ + n)*4 + d] = v;
        }
    } else {
        int nh = n - H_;
        for (int d = 0; d < 3; ++d) x[g*4 + d] = x_hv[(b*NH_ + nh)*3 + d];
    }
}

__global__ void k_edges(const int* __restrict__ ehh, const float* __restrict__ em_hh,
                        const float* __restrict__ em_hv, const float* __restrict__ bond,
                        int* __restrict__ erow, int* __restrict__ ecol,
                        float* __restrict__ emk, float* __restrict__ ebd)
{
    int g = blockIdx.x * blockDim.x + threadIdx.x;
    if (g >= B_ * NE_) return;
    int b = g / NE_, e = g % NE_;
    int r, c; float em, bd;
    if (e < EHH_) {
        r = ehh[(b*EHH_ + e)*2 + 0];
        c = ehh[(b*EHH_ + e)*2 + 1];
        em = em_hh[b*EHH_ + e];
        bd = 0.0f;
    } else {
        int k = e - EHH_;
        r = k / NH_; int cc = k % NH_; c = H_ + cc;
        em = em_hv[(b*H_ + r)*NH_ + cc];
        bd = bond [(b*H_ + r)*NH_ + cc];
    }
    erow[g] = r; ecol[g] = c; emk[g] = em; ebd[g] = bd;
}

// ---------------- per-layer: node @ W1 precompute ----------------
// hiW1[bs,h]  = feat[bs,h,:] @ W1[l, 0:79, :]      (rows are always hydrogens)
// hjW1[bs,n]  = feat[bs,n,:] @ W1[l, 79:158, :]    (all 250 nodes)
__global__ __launch_bounds__(HID_) void k_nodeW1(const float* __restrict__ feat,
                                                 const float* __restrict__ W1, int l,
                                                 float* __restrict__ hiW1,
                                                 float* __restrict__ hjW1)
{
    __shared__ float sf[FDIM_];
    int node = blockIdx.x;              // bs*NN + n
    int bs = node / NN_, n = node % NN_;
    int t = threadIdx.x;
    if (t < FDIM_) sf[t] = feat[node*FS_ + t];
    __syncthreads();
    const float* W1l = W1 + l*EDIM_*HID_;
    float aj = 0.0f, ai = 0.0f;
    bool isH = (n < H_);
    for (int f = 0; f < FDIM_; ++f) {
        float v = sf[f];
        aj += v * W1l[(FDIM_ + f)*HID_ + t];
        if (isH) ai += v * W1l[f*HID_ + t];
    }
    hjW1[node*HID_ + t] = aj;
    if (isH) hiW1[(bs*H_ + n)*HID_ + t] = ai;
}

// ---------------- per-layer: fused edge MLP + segment aggregation ----------------
#define FMA16(WPTR)                                                     \
    {                                                                   \
        const float4* w4 = (const float4*)((WPTR));                     \
        float4 w0 = w4[0], w1 = w4[1], w2 = w4[2], w3 = w4[3];          \
        acc[0]  += a*w0.x; acc[1]  += a*w0.y; acc[2]  += a*w0.z; acc[3]  += a*w0.w; \
        acc[4]  += a*w1.x; acc[5]  += a*w1.y; acc[6]  += a*w1.z; acc[7]  += a*w1.w; \
        acc[8]  += a*w2.x; acc[9]  += a*w2.y; acc[10] += a*w2.z; acc[11] += a*w2.w; \
        acc[12] += a*w3.x; acc[13] += a*w3.y; acc[14] += a*w3.z; acc[15] += a*w3.w; \
    }

__global__ __launch_bounds__(256) void k_edge_mlp(
    const float* __restrict__ x, const float* __restrict__ hiW1,
    const float* __restrict__ hjW1,
    const int* __restrict__ erow, const int* __restrict__ ecol,
    const float* __restrict__ emk, const float* __restrict__ ebd,
    const float* __restrict__ t_in,
    const float* __restrict__ W1, const float* __restrict__ b1,
    const float* __restrict__ W2, const float* __restrict__ b2,
    const float* __restrict__ Wc1, const float* __restrict__ bc1,
    const float* __restrict__ Wc2, int l,
    float* __restrict__ aggx, float* __restrict__ aggm)
{
    __shared__ float s_m1[TE_][HID_ + 4];
    __shared__ float s_m [TE_][HID_ + 4];
    __shared__ float s_diff[TE_][4];
    __shared__ float s_scal[TE_][4];    // dist, bond, emask
    __shared__ int   s_row[TE_];
    __shared__ int   s_col[TE_];
    __shared__ float s_part[TE_][8];
    __shared__ float s_cw[TE_];

    int g0 = blockIdx.x * TE_;
    int bs = g0 / NE_;                  // all 32 edges share (b,s): 10400 % 32 == 0
    int e0 = g0 % NE_;
    int b  = bs / S_;
    int t  = threadIdx.x;
    float tb = t_in[b];

    if (t < TE_) {
        int i  = t;
        int ge = b*NE_ + e0 + i;
        int row = erow[ge], col = ecol[ge];
        s_row[i] = row; s_col[i] = col;
        float dx0 = x[(bs*NN_ + row)*4 + 0] - x[(bs*NN_ + col)*4 + 0];
        float dx1 = x[(bs*NN_ + row)*4 + 1] - x[(bs*NN_ + col)*4 + 1];
        float dx2 = x[(bs*NN_ + row)*4 + 2] - x[(bs*NN_ + col)*4 + 2];
        s_diff[i][0] = dx0; s_diff[i][1] = dx1; s_diff[i][2] = dx2;
        s_scal[i][0] = sqrtf(dx0*dx0 + dx1*dx1 + dx2*dx2);
        s_scal[i][1] = ebd[ge];
        s_scal[i][2] = emk[ge];
    }
    __syncthreads();

    int i  = t >> 3;                    // edge within block
    int j0 = (t & 7) * 16;              // output-dim group
    const float* W1l = W1 + l*EDIM_*HID_;
    const float* b1l = b1 + l*HID_;
    float dist = s_scal[i][0], bond = s_scal[i][1], em = s_scal[i][2];
    int row = s_row[i], col = s_col[i];

    // stage 1: m1 = silu(hiW1[row] + hjW1[col] + dist*W1[158] + bond*W1[159] + t*W1[160] + b1)
    {
        const float* pi   = hiW1 + (bs*H_  + row)*HID_ + j0;
        const float* pj   = hjW1 + (bs*NN_ + col)*HID_ + j0;
        const float* w158 = W1l + 158*HID_ + j0;
        const float* w159 = W1l + 159*HID_ + j0;
        const float* w160 = W1l + 160*HID_ + j0;
        #pragma unroll
        for (int u = 0; u < 16; ++u) {
            float v = pi[u] + pj[u] + dist*w158[u] + bond*w159[u] + tb*w160[u] + b1l[j0 + u];
            s_m1[i][j0 + u] = silu_(v);
        }
    }
    __syncthreads();

    // stage 2: m = silu(m1 @ W2 + b2) * emask
    float acc[16];
    {
        const float* W2l = W2 + l*HID_*HID_;
        const float* b2l = b2 + l*HID_;
        #pragma unroll
        for (int u = 0; u < 16; ++u) acc[u] = b2l[j0 + u];
        for (int k = 0; k < HID_; ++k) {
            float a = s_m1[i][k];
            FMA16(W2l + k*HID_ + j0);
        }
        #pragma unroll
        for (int u = 0; u < 16; ++u) s_m[i][j0 + u] = silu_(acc[u]) * em;
    }
    __syncthreads();

    // stage 3: cw = silu(m @ Wc1 + bc1) @ Wc2
    {
        const float* Wc1l = Wc1 + l*HID_*HID_;
        const float* bc1l = bc1 + l*HID_;
        const float* Wc2l = Wc2 + l*HID_;
        #pragma unroll
        for (int u = 0; u < 16; ++u) acc[u] = bc1l[j0 + u];
        for (int k = 0; k < HID_; ++k) {
            float a = s_m[i][k];
            FMA16(Wc1l + k*HID_ + j0);
        }
        float part = 0.0f;
        #pragma unroll
        for (int u = 0; u < 16; ++u) part += silu_(acc[u]) * Wc2l[j0 + u];
        s_part[i][t & 7] = part;
    }
    __syncthreads();
    if ((t & 7) == 0) {
        float cw = 0.0f;
        #pragma unroll
        for (int q = 0; q < 8; ++q) cw += s_part[i][q];
        s_cw[i] = cw;
    }
    __syncthreads();

    // aggregation: run-length compress by row (grid edges are row-sorted)
    if (t < HID_) {
        int j = t;
        float run = 0.0f; int crow = s_row[0];
        for (int i2 = 0; i2 < TE_; ++i2) {
            int r2 = s_row[i2];
            if (r2 != crow) {
                atomicAdd(&aggm[(bs*H_ + crow)*HID_ + j], run);
                run = 0.0f; crow = r2;
            }
            run += s_m[i2][j];
        }
        atomicAdd(&aggm[(bs*H_ + crow)*HID_ + j], run);
    } else if (t < HID_ + 3) {
        int d = t - HID_;
        float run = 0.0f; int crow = s_row[0];
        for (int i2 = 0; i2 < TE_; ++i2) {
            int r2 = s_row[i2];
            if (r2 != crow) {
                atomicAdd(&aggx[(bs*H_ + crow)*4 + d], run);
                run = 0.0f; crow = r2;
            }
            run += s_diff[i2][d] * s_cw[i2];
        }
        atomicAdd(&aggx[(bs*H_ + crow)*4 + d], run);
    }
}

// ---------------- per-layer: node update ----------------
__global__ __launch_bounds__(HID_) void k_node_update(
    float* __restrict__ feat, float* __restrict__ x,
    const float* __restrict__ aggm, const float* __restrict__ aggx,
    const float* __restrict__ Wn1, const float* __restrict__ bn1,
    const float* __restrict__ Wn2, const float* __restrict__ bn2, int l)
{
    __shared__ float s_in[FDIM_ + HID_];   // 207
    __shared__ float s_u[HID_];
    int node = blockIdx.x;                 // bs*H + h
    int bs = node / H_, h = node % H_;
    int t = threadIdx.x;
    for (int idx = t; idx < FDIM_ + HID_; idx += HID_)
        s_in[idx] = (idx < FDIM_) ? feat[(bs*NN_ + h)*FS_ + idx]
                                  : aggm[node*HID_ + (idx - FDIM_)];
    __syncthreads();
    const float* Wn1l = Wn1 + l*(FDIM_ + HID_)*HID_;
    float acc = bn1[l*HID_ + t];
    for (int k = 0; k < FDIM_ + HID_; ++k) acc += s_in[k] * Wn1l[k*HID_ + t];
    s_u[t] = silu_(acc);
    __syncthreads();
    if (t < FDIM_) {
        const float* Wn2l = Wn2 + l*HID_*FDIM_;
        float a2 = bn2[l*FDIM_ + t];
        for (int k = 0; k < HID_; ++k) a2 += s_u[k] * Wn2l[k*FDIM_ + t];
        feat[(bs*NN_ + h)*FS_ + t] = s_in[t] + a2;     // h_out = h_h + ... (+bn2)
    } else if (t < FDIM_ + 3) {
        int d = t - FDIM_;
        x[(bs*NN_ + h)*4 + d] += aggx[node*4 + d];
    }
}

// ---------------- final output ----------------
__global__ void k_out(const float* __restrict__ x, const float* __restrict__ x0h,
                      const float* __restrict__ amask, float* __restrict__ out)
{
    int g = blockIdx.x * blockDim.x + threadIdx.x;
    if (g >= BS_ * H_ * 3) return;
    int d = g % 3; int nh = g / 3; int h = nh % H_; int bs = nh / H_; int b = bs / S_;
    out[g] = (x[(bs*NN_ + h)*4 + d] - x0h[nh*4 + d]) * amask[b*H_ + h];
}

// ---------------- launch ----------------
extern "C" void kernel_launch(void* const* d_in, const int* in_sizes, int n_in,
                              void* d_out, int out_size, void* d_ws, size_t ws_size,
                              hipStream_t stream)
{
    const float* t_in  = (const float*)d_in[0];
    const float* x_h   = (const float*)d_in[1];
    const float* x_hv  = (const float*)d_in[2];
    const float* bond  = (const float*)d_in[3];
    const float* em_hv = (const float*)d_in[4];
    const float* em_hh = (const float*)d_in[5];
    const float* amask = (const float*)d_in[6];
    const float* W1    = (const float*)d_in[7];
    const float* b1    = (const float*)d_in[8];
    const float* W2    = (const float*)d_in[9];
    const float* b2    = (const float*)d_in[10];
    const float* Wc1   = (const float*)d_in[11];
    const float* bc1   = (const float*)d_in[12];
    const float* Wc2   = (const float*)d_in[13];
    const float* Wn1   = (const float*)d_in[14];
    const float* bn1   = (const float*)d_in[15];
    const float* Wn2   = (const float*)d_in[16];
    const float* bn2   = (const float*)d_in[17];
    const int* pep     = (const int*)d_in[18];
    const int* lab_hv  = (const int*)d_in[19];
    const int* lab_h   = (const int*)d_in[20];
    const int* pos_hv  = (const int*)d_in[21];
    const int* pos_h   = (const int*)d_in[22];
    const int* ehh     = (const int*)d_in[23];
    const int* bound   = (const int*)d_in[24];

    float* ws   = (float*)d_ws;
    float* feat = ws + OFF_FEAT;
    float* x    = ws + OFF_X;
    float* x0h  = ws + OFF_X0H;
    int*   erow = (int*)(ws + OFF_EROW);
    int*   ecol = (int*)(ws + OFF_ECOL);
    float* emk  = ws + OFF_EMASK;
    float* ebd  = ws + OFF_EBOND;
    float* aggx = ws + OFF_AGGX;
    float* aggm = ws + OFF_AGGM;
    float* hiW1 = ws + OFF_HIW1;
    float* hjW1 = ws + OFF_HJW1;

    hipLaunchKernelGGL(k_embed, dim3((B_*NN_ + 255)/256), dim3(256), 0, stream,
                       lab_h, pos_h, lab_hv, pos_hv, pep, feat);
    hipLaunchKernelGGL(k_xinit, dim3((BS_*NN_ + 255)/256), dim3(256), 0, stream,
                       x_h, x_hv, bound, x, x0h);
    hipLaunchKernelGGL(k_edges, dim3((B_*NE_ + 255)/256), dim3(256), 0, stream,
                       ehh, em_hh, em_hv, bond, erow, ecol, emk, ebd);

    for (int l = 0; l < L_; ++l) {
        hipMemsetAsync(aggx, 0, (size_t)(BS_*H_*4 + BS_*H_*HID_) * sizeof(float), stream);
        hipLaunchKernelGGL(k_nodeW1, dim3(BS_*NN_), dim3(HID_), 0, stream,
                           feat, W1, l, hiW1, hjW1);
        hipLaunchKernelGGL(k_edge_mlp, dim3(TOTE_/TE_), dim3(256), 0, stream,
                           x, hiW1, hjW1, erow, ecol, emk, ebd, t_in,
                           W1, b1, W2, b2, Wc1, bc1, Wc2, l, aggx, aggm);
        hipLaunchKernelGGL(k_node_update, dim3(BS_*H_), dim3(HID_), 0, stream,
                           feat, x, aggm, aggx, Wn1, bn1, Wn2, bn2, l);
    }

    hipLaunchKernelGGL(k_out, dim3((BS_*H_*3 + 255)/256), dim3(256), 0, stream,
                       x, x0h, amask, (float*)d_out);
}

// Round 2
// 722.824 us; speedup vs baseline: 6.8609x; 6.8609x over previous
//
#include <hip/hip_runtime.h>
#include <math.h>

// Problem constants
#define B_     8
#define S_     4
#define H_     50
#define NH_    200
#define EHH_   400
#define L_     2
#define HID_   128
#define FDIM_  79          // 44 + 20 + 15
#define EDIM_  161         // 2*FDIM + 3
#define NN_    250         // H + NH
#define NE_    10400       // EHH + H*NH
#define BS_    32          // B*S
#define TOTE_  (BS_*NE_)   // 332800
#define FS_    80          // feat row stride (pad 79 -> 80)
#define TE_    64          // edges per block in edge kernel
#define MSTR_  136         // LDS tile stride in bf16 (128 + 8 pad -> 2-way bank max)

// Workspace layout (float offsets)
#define OFF_FEAT   0                         // BS*NN*FS = 640000
#define OFF_X      640000                    // BS*NN*4  = 32000
#define OFF_X0H    672000                    // BS*H*4   = 6400
#define OFF_EROW   678400                    // B*NE (int) = 83200
#define OFF_ECOL   761600                    // 83200
#define OFF_EMASK  844800                    // 83200
#define OFF_EBOND  928000                    // 83200
#define OFF_AGGX   1011200                   // BS*H*4   = 6400
#define OFF_AGGM   1017600                   // BS*H*HID = 204800
#define OFF_HIW1   1222400                   // BS*H*HID = 204800
#define OFF_HJW1   1427200                   // BS*NN*HID = 1024000
#define OFF_WP     2451200                   // packed bf16 W2/Wc1: 2 layers*2 mats*16384 ushort = 32768 floats
// total = 2483968 floats ~= 9.94 MB

typedef __attribute__((ext_vector_type(8))) short short8;
typedef __attribute__((ext_vector_type(4))) float f32x4;

__device__ __forceinline__ float silu_(float v) {
    return v * (1.0f / (1.0f + __expf(-v)));
}
__device__ __forceinline__ unsigned short f2bf(float f) {
    unsigned int u = __float_as_uint(f);
    unsigned int r = (u + 0x7fffu + ((u >> 16) & 1u)) >> 16;
    return (unsigned short)r;
}
__device__ __forceinline__ float bf2f(unsigned short v) {
    return __uint_as_float(((unsigned int)v) << 16);
}

// ---------------- setup kernels ----------------

__global__ void k_embed(const int* __restrict__ lab_h, const int* __restrict__ pos_h,
                        const int* __restrict__ lab_hv, const int* __restrict__ pos_hv,
                        const int* __restrict__ pep, float* __restrict__ feat)
{
    int g = blockIdx.x * blockDim.x + threadIdx.x;
    if (g >= B_ * NN_) return;
    int b = g / NN_, n = g % NN_;
    int label, pos;
    if (n < H_) { label = lab_h[b*H_ + n];        pos = pos_h[b*H_ + n]; }
    else        { int nh = n - H_; label = lab_hv[b*NH_ + nh]; pos = pos_hv[b*NH_ + nh]; }
    int aa = pep[b*15 + (pos - 1)];
    for (int f = 0; f < FDIM_; ++f) {
        float v;
        if (f < 44)      v = (f == label)        ? 1.0f : 0.0f;
        else if (f < 64) v = ((f - 44) == aa)     ? 1.0f : 0.0f;
        else             v = ((f - 64) == pos - 1)? 1.0f : 0.0f;
        for (int s = 0; s < S_; ++s)
            feat[(((b*S_ + s)*NN_) + n)*FS_ + f] = v;
    }
}

__global__ void k_xinit(const float* __restrict__ x_h, const float* __restrict__ x_hv,
                        const int* __restrict__ bound, float* __restrict__ x,
                        float* __restrict__ x0h)
{
    int g = blockIdx.x * blockDim.x + threadIdx.x;
    if (g >= BS_ * NN_) return;
    int bs = g / NN_, n = g % NN_;
    int b = bs / S_;
    if (n < H_) {
        int ba = bound[b*H_ + n];
        for (int d = 0; d < 3; ++d) {
            float v = x_h[(bs*H_ + n)*3 + d] + x_hv[(b*NH_ + ba)*3 + d];
            x[g*4 + d] = v;
            x0h[(bs*H_ + n)*4 + d] = v;
        }
    } else {
        int nh = n - H_;
        for (int d = 0; d < 3; ++d) x[g*4 + d] = x_hv[(b*NH_ + nh)*3 + d];
    }
}

__global__ void k_edges(const int* __restrict__ ehh, const float* __restrict__ em_hh,
                        const float* __restrict__ em_hv, const float* __restrict__ bond,
                        int* __restrict__ erow, int* __restrict__ ecol,
                        float* __restrict__ emk, float* __restrict__ ebd)
{
    int g = blockIdx.x * blockDim.x + threadIdx.x;
    if (g >= B_ * NE_) return;
    int b = g / NE_, e = g % NE_;
    int r, c; float em, bd;
    if (e < EHH_) {
        r = ehh[(b*EHH_ + e)*2 + 0];
        c = ehh[(b*EHH_ + e)*2 + 1];
        em = em_hh[b*EHH_ + e];
        bd = 0.0f;
    } else {
        int k = e - EHH_;
        r = k / NH_; int cc = k % NH_; c = H_ + cc;
        em = em_hv[(b*H_ + r)*NH_ + cc];
        bd = bond [(b*H_ + r)*NH_ + cc];
    }
    erow[g] = r; ecol[g] = c; emk[g] = em; ebd[g] = bd;
}

// ---------------- weight packing: W2/Wc1 -> bf16 B-fragment layout ----------------
// Wp[l][mat][ ((kc*128 + n)*4 + q)*8 + j ] = bf16( W[l][kc*32 + q*8 + j][n] )
__global__ void k_packW(const float* __restrict__ W2, const float* __restrict__ Wc1,
                        unsigned short* __restrict__ Wp)
{
    int g = blockIdx.x * blockDim.x + threadIdx.x;
    if (g >= 2*2*16384) return;
    int idx = g & 16383;
    int lm  = g >> 14;
    int l   = lm >> 1, mat = lm & 1;
    int j  = idx & 7;
    int q  = (idx >> 3) & 3;
    int n  = (idx >> 5) & 127;
    int kc = idx >> 12;
    int k  = kc*32 + q*8 + j;
    const float* W = (mat == 0 ? W2 : Wc1) + l*HID_*HID_;
    Wp[g] = f2bf(W[k*HID_ + n]);
}

// ---------------- per-layer: node @ W1 precompute ----------------
__global__ __launch_bounds__(HID_) void k_nodeW1(const float* __restrict__ feat,
                                                 const float* __restrict__ W1, int l,
                                                 float* __restrict__ hiW1,
                                                 float* __restrict__ hjW1)
{
    __shared__ float sf[FDIM_];
    int node = blockIdx.x;              // bs*NN + n
    int bs = node / NN_, n = node % NN_;
    int t = threadIdx.x;
    if (t < FDIM_) sf[t] = feat[node*FS_ + t];
    __syncthreads();
    const float* W1l = W1 + l*EDIM_*HID_;
    float aj = 0.0f, ai = 0.0f;
    bool isH = (n < H_);
    for (int f = 0; f < FDIM_; ++f) {
        float v = sf[f];
        aj += v * W1l[(FDIM_ + f)*HID_ + t];
        if (isH) ai += v * W1l[f*HID_ + t];
    }
    hjW1[node*HID_ + t] = aj;
    if (isH) hiW1[(bs*H_ + n)*HID_ + t] = ai;
}

// ---------------- per-layer: fused MFMA edge MLP + segment aggregation ----------------
__global__ __launch_bounds__(256) void k_edge_mlp(
    const float* __restrict__ x, const float* __restrict__ hiW1,
    const float* __restrict__ hjW1,
    const int* __restrict__ erow, const int* __restrict__ ecol,
    const float* __restrict__ emk, const float* __restrict__ ebd,
    const float* __restrict__ t_in,
    const float* __restrict__ W1, const float* __restrict__ b1,
    const float* __restrict__ b2, const float* __restrict__ bc1,
    const float* __restrict__ Wc2,
    const unsigned short* __restrict__ Wp, int l,
    float* __restrict__ aggx, float* __restrict__ aggm)
{
    __shared__ unsigned short s_m1[TE_][MSTR_];   // bf16 m1 tile (A of GEMM-2)
    __shared__ unsigned short s_m [TE_][MSTR_];   // bf16 m  tile (A of GEMM-3)
    __shared__ float s_diff[TE_][4];
    __shared__ float s_db  [TE_][2];              // dist, bond
    __shared__ float s_emk [TE_];
    __shared__ float s_tb  [TE_];
    __shared__ int   s_ii  [TE_];                 // bs*H + row  (== agg target)
    __shared__ int   s_jj  [TE_];                 // bs*NN + col
    __shared__ float s_cw  [TE_];
    float* s_part = (float*)s_m1;                 // aliased [64][17] after stage-2 A reads

    const int t = threadIdx.x;
    const int lane = t & 63, w = t >> 6;
    const int l15 = lane & 15, q = lane >> 4;
    const int g0 = blockIdx.x * TE_;

    // ---- setup: per-edge scalars ----
    if (t < TE_) {
        int ge = g0 + t;
        int bs = ge / NE_;
        int e  = ge - bs*NE_;
        int b  = bs / S_;
        int row = erow[b*NE_ + e], col = ecol[b*NE_ + e];
        s_ii[t] = bs*H_ + row;
        s_jj[t] = bs*NN_ + col;
        float dx0 = x[(bs*NN_ + row)*4 + 0] - x[(bs*NN_ + col)*4 + 0];
        float dx1 = x[(bs*NN_ + row)*4 + 1] - x[(bs*NN_ + col)*4 + 1];
        float dx2 = x[(bs*NN_ + row)*4 + 2] - x[(bs*NN_ + col)*4 + 2];
        s_diff[t][0] = dx0; s_diff[t][1] = dx1; s_diff[t][2] = dx2;
        s_db[t][0] = sqrtf(dx0*dx0 + dx1*dx1 + dx2*dx2);
        s_db[t][1] = ebd[b*NE_ + e];
        s_emk[t]   = emk[b*NE_ + e];
        s_tb[t]    = t_in[b];
    }
    __syncthreads();

    // ---- stage 1: m1 = silu(hiW1[row] + hjW1[col] + dist*w158 + bond*w159 + t*w160 + b1) ----
    {
        int i  = t >> 2;
        int k0 = (t & 3) * 32;
        const float* pi   = hiW1 + (size_t)s_ii[i]*HID_ + k0;
        const float* pj   = hjW1 + (size_t)s_jj[i]*HID_ + k0;
        const float* W1l  = W1 + l*EDIM_*HID_;
        const float* w158 = W1l + 158*HID_ + k0;
        const float* w159 = W1l + 159*HID_ + k0;
        const float* w160 = W1l + 160*HID_ + k0;
        const float* b1l  = b1 + l*HID_ + k0;
        float dist = s_db[i][0], bond = s_db[i][1], tb = s_tb[i];
        #pragma unroll
        for (int u = 0; u < 32; u += 4) {
            float4 a  = *(const float4*)(pi + u);
            float4 c4 = *(const float4*)(pj + u);
            float4 wa = *(const float4*)(w158 + u);
            float4 wb = *(const float4*)(w159 + u);
            float4 wc = *(const float4*)(w160 + u);
            float4 bb = *(const float4*)(b1l + u);
            s_m1[i][k0+u+0] = f2bf(silu_(a.x + c4.x + dist*wa.x + bond*wb.x + tb*wc.x + bb.x));
            s_m1[i][k0+u+1] = f2bf(silu_(a.y + c4.y + dist*wa.y + bond*wb.y + tb*wc.y + bb.y));
            s_m1[i][k0+u+2] = f2bf(silu_(a.z + c4.z + dist*wa.z + bond*wb.z + tb*wc.z + bb.z));
            s_m1[i][k0+u+3] = f2bf(silu_(a.w + c4.w + dist*wa.w + bond*wb.w + tb*wc.w + bb.w));
        }
    }
    __syncthreads();

    const int mrow = w*16 + l15;   // this lane's A-row (edge index) for MFMA

    // ---- stage 2: m = silu(m1 @ W2 + b2) * emask  (MFMA) ----
    {
        short8 afrag[4];
        #pragma unroll
        for (int kc = 0; kc < 4; ++kc)
            afrag[kc] = *(const short8*)&s_m1[mrow][kc*32 + q*8];
        const unsigned short* Wp2 = Wp + (size_t)(l*2 + 0)*16384;
        f32x4 acc[8];
        #pragma unroll
        for (int nt = 0; nt < 8; ++nt) {
            f32x4 c = {0.f, 0.f, 0.f, 0.f};
            #pragma unroll
            for (int kc = 0; kc < 4; ++kc) {
                short8 bfrag = *(const short8*)&Wp2[((kc*128 + nt*16 + l15)*4 + q)*8];
                c = __builtin_amdgcn_mfma_f32_16x16x32_bf16(afrag[kc], bfrag, c, 0, 0, 0);
            }
            acc[nt] = c;
        }
        const float* b2l = b2 + l*HID_;
        #pragma unroll
        for (int nt = 0; nt < 8; ++nt) {
            int colj = nt*16 + l15;
            float bias = b2l[colj];
            #pragma unroll
            for (int r = 0; r < 4; ++r) {
                int rowe = w*16 + q*4 + r;
                float v = silu_(acc[nt][r] + bias) * s_emk[rowe];
                s_m[rowe][colj] = f2bf(v);
            }
        }
    }
    // barrier: ensures every wave's stage-2 A-reads of s_m1 complete before any
    // wave's stage-3 epilogue writes s_part (aliased onto s_m1)
    __syncthreads();

    // ---- stage 3: cw = silu(m @ Wc1 + bc1) @ Wc2  (MFMA) ----
    {
        short8 afrag[4];
        #pragma unroll
        for (int kc = 0; kc < 4; ++kc)
            afrag[kc] = *(const short8*)&s_m[mrow][kc*32 + q*8];
        const unsigned short* Wp3 = Wp + (size_t)(l*2 + 1)*16384;
        f32x4 acc[8];
        #pragma unroll
        for (int nt = 0; nt < 8; ++nt) {
            f32x4 c = {0.f, 0.f, 0.f, 0.f};
            #pragma unroll
            for (int kc = 0; kc < 4; ++kc) {
                short8 bfrag = *(const short8*)&Wp3[((kc*128 + nt*16 + l15)*4 + q)*8];
                c = __builtin_amdgcn_mfma_f32_16x16x32_bf16(afrag[kc], bfrag, c, 0, 0, 0);
            }
            acc[nt] = c;
        }
        const float* bc1l = bc1 + l*HID_;
        const float* wc2l = Wc2 + l*HID_;
        float p[4] = {0.f, 0.f, 0.f, 0.f};
        #pragma unroll
        for (int nt = 0; nt < 8; ++nt) {
            int colj = nt*16 + l15;
            float bias = bc1l[colj];
            float wcv  = wc2l[colj];
            #pragma unroll
            for (int r = 0; r < 4; ++r)
                p[r] += silu_(acc[nt][r] + bias) * wcv;
        }
        #pragma unroll
        for (int r = 0; r < 4; ++r)
            s_part[(w*16 + q*4 + r)*17 + l15] = p[r];
    }
    __syncthreads();

    if (t < TE_) {
        float cw = 0.f;
        #pragma unroll
        for (int c = 0; c < 16; ++c) cw += s_part[t*17 + c];
        s_cw[t] = cw;
    }
    __syncthreads();

    // ---- aggregation: run-length compress by target (bs*H+row), then atomics ----
    if (t < HID_) {
        int j = t;
        float run = 0.f; int ct = s_ii[0];
        for (int i2 = 0; i2 < TE_; ++i2) {
            int tg = s_ii[i2];
            if (tg != ct) {
                atomicAdd(&aggm[(size_t)ct*HID_ + j], run);
                run = 0.f; ct = tg;
            }
            run += bf2f(s_m[i2][j]);
        }
        atomicAdd(&aggm[(size_t)ct*HID_ + j], run);
    } else if (t < HID_ + 3) {
        int d = t - HID_;
        float run = 0.f; int ct = s_ii[0];
        for (int i2 = 0; i2 < TE_; ++i2) {
            int tg = s_ii[i2];
            if (tg != ct) {
                atomicAdd(&aggx[(size_t)ct*4 + d], run);
                run = 0.f; ct = tg;
            }
            run += s_diff[i2][d] * s_cw[i2];
        }
        atomicAdd(&aggx[(size_t)ct*4 + d], run);
    }
}

// ---------------- per-layer: node update ----------------
__global__ __launch_bounds__(HID_) void k_node_update(
    float* __restrict__ feat, float* __restrict__ x,
    const float* __restrict__ aggm, const float* __restrict__ aggx,
    const float* __restrict__ Wn1, const float* __restrict__ bn1,
    const float* __restrict__ Wn2, const float* __restrict__ bn2, int l)
{
    __shared__ float s_in[FDIM_ + HID_];   // 207
    __shared__ float s_u[HID_];
    int node = blockIdx.x;                 // bs*H + h
    int bs = node / H_, h = node % H_;
    int t = threadIdx.x;
    for (int idx = t; idx < FDIM_ + HID_; idx += HID_)
        s_in[idx] = (idx < FDIM_) ? feat[(bs*NN_ + h)*FS_ + idx]
                                  : aggm[node*HID_ + (idx - FDIM_)];
    __syncthreads();
    const float* Wn1l = Wn1 + l*(FDIM_ + HID_)*HID_;
    float acc = bn1[l*HID_ + t];
    for (int k = 0; k < FDIM_ + HID_; ++k) acc += s_in[k] * Wn1l[k*HID_ + t];
    s_u[t] = silu_(acc);
    __syncthreads();
    if (t < FDIM_) {
        const float* Wn2l = Wn2 + l*HID_*FDIM_;
        float a2 = bn2[l*FDIM_ + t];
        for (int k = 0; k < HID_; ++k) a2 += s_u[k] * Wn2l[k*FDIM_ + t];
        feat[(bs*NN_ + h)*FS_ + t] = s_in[t] + a2;
    } else if (t < FDIM_ + 3) {
        int d = t - FDIM_;
        x[(bs*NN_ + h)*4 + d] += aggx[node*4 + d];
    }
}

// ---------------- final output ----------------
__global__ void k_out(const float* __restrict__ x, const float* __restrict__ x0h,
                      const float* __restrict__ amask, float* __restrict__ out)
{
    int g = blockIdx.x * blockDim.x + threadIdx.x;
    if (g >= BS_ * H_ * 3) return;
    int d = g % 3; int nh = g / 3; int h = nh % H_; int bs = nh / H_; int b = bs / S_;
    out[g] = (x[(bs*NN_ + h)*4 + d] - x0h[nh*4 + d]) * amask[b*H_ + h];
}

// ---------------- launch ----------------
extern "C" void kernel_launch(void* const* d_in, const int* in_sizes, int n_in,
                              void* d_out, int out_size, void* d_ws, size_t ws_size,
                              hipStream_t stream)
{
    const float* t_in  = (const float*)d_in[0];
    const float* x_h   = (const float*)d_in[1];
    const float* x_hv  = (const float*)d_in[2];
    const float* bond  = (const float*)d_in[3];
    const float* em_hv = (const float*)d_in[4];
    const float* em_hh = (const float*)d_in[5];
    const float* amask = (const float*)d_in[6];
    const float* W1    = (const float*)d_in[7];
    const float* b1    = (const float*)d_in[8];
    const float* W2    = (const float*)d_in[9];
    const float* b2    = (const float*)d_in[10];
    const float* Wc1   = (const float*)d_in[11];
    const float* bc1   = (const float*)d_in[12];
    const float* Wc2   = (const float*)d_in[13];
    const float* Wn1   = (const float*)d_in[14];
    const float* bn1   = (const float*)d_in[15];
    const float* Wn2   = (const float*)d_in[16];
    const float* bn2   = (const float*)d_in[17];
    const int* pep     = (const int*)d_in[18];
    const int* lab_hv  = (const int*)d_in[19];
    const int* lab_h   = (const int*)d_in[20];
    const int* pos_hv  = (const int*)d_in[21];
    const int* pos_h   = (const int*)d_in[22];
    const int* ehh     = (const int*)d_in[23];
    const int* bound   = (const int*)d_in[24];

    float* ws   = (float*)d_ws;
    float* feat = ws + OFF_FEAT;
    float* x    = ws + OFF_X;
    float* x0h  = ws + OFF_X0H;
    int*   erow = (int*)(ws + OFF_EROW);
    int*   ecol = (int*)(ws + OFF_ECOL);
    float* emk  = ws + OFF_EMASK;
    float* ebd  = ws + OFF_EBOND;
    float* aggx = ws + OFF_AGGX;
    float* aggm = ws + OFF_AGGM;
    float* hiW1 = ws + OFF_HIW1;
    float* hjW1 = ws + OFF_HJW1;
    unsigned short* Wp = (unsigned short*)(ws + OFF_WP);

    hipLaunchKernelGGL(k_embed, dim3((B_*NN_ + 255)/256), dim3(256), 0, stream,
                       lab_h, pos_h, lab_hv, pos_hv, pep, feat);
    hipLaunchKernelGGL(k_xinit, dim3((BS_*NN_ + 255)/256), dim3(256), 0, stream,
                       x_h, x_hv, bound, x, x0h);
    hipLaunchKernelGGL(k_edges, dim3((B_*NE_ + 255)/256), dim3(256), 0, stream,
                       ehh, em_hh, em_hv, bond, erow, ecol, emk, ebd);
    hipLaunchKernelGGL(k_packW, dim3((2*2*16384 + 255)/256), dim3(256), 0, stream,
                       W2, Wc1, Wp);

    for (int l = 0; l < L_; ++l) {
        hipMemsetAsync(aggx, 0, (size_t)(BS_*H_*4 + BS_*H_*HID_) * sizeof(float), stream);
        hipLaunchKernelGGL(k_nodeW1, dim3(BS_*NN_), dim3(HID_), 0, stream,
                           feat, W1, l, hiW1, hjW1);
        hipLaunchKernelGGL(k_edge_mlp, dim3(TOTE_/TE_), dim3(256), 0, stream,
                           x, hiW1, hjW1, erow, ecol, emk, ebd, t_in,
                           W1, b1, b2, bc1, Wc2, Wp, l, aggx, aggm);
        hipLaunchKernelGGL(k_node_update, dim3(BS_*H_), dim3(HID_), 0, stream,
                           feat, x, aggm, aggx, Wn1, bn1, Wn2, bn2, l);
    }

    hipLaunchKernelGGL(k_out, dim3((BS_*H_*3 + 255)/256), dim3(256), 0, stream,
                       x, x0h, amask, (float*)d_out);
}

// Round 3
// 573.718 us; speedup vs baseline: 8.6440x; 1.2599x over previous
//
#include <hip/hip_runtime.h>
#include <math.h>

// Problem constants
#define B_     8
#define S_     4
#define H_     50
#define NH_    200
#define EHH_   400
#define L_     2
#define HID_   128
#define FDIM_  79          // 44 + 20 + 15
#define EDIM_  161         // 2*FDIM + 3
#define NN_    250         // H + NH
#define NE_    10400       // EHH + H*NH
#define BS_    32          // B*S
#define TOTE_  (BS_*NE_)   // 332800
#define FS_    80          // feat row stride
#define TE_    64          // edges per block in edge kernel
#define MSTR_  136         // s_m stride in bf16 (128 + 8)
#define NDIM_  207         // FDIM + HID

// Workspace layout (float offsets)
#define OFF_FEATH  0        // BS*H*80   = 128000
#define OFF_FEATHV 128000   // B*NH*80   = 128000
#define OFF_X      256000   // BS*NN*4   = 32000
#define OFF_X0H    288000   // BS*H*4    = 6400
#define OFF_EROW   294400   // 83200 (int)
#define OFF_ECOL   377600   // 83200 (int)
#define OFF_EMASK  460800   // 83200
#define OFF_EBOND  544000   // 83200
#define OFF_AGGX   627200   // 6400   (contiguous with AGGM for fused zeroing)
#define OFF_AGGM   633600   // 204800
#define OFF_HIW1   838400   // BS*H*128 = 204800
#define OFF_HJW1   1043200  // (BS*H + B*NH)*128 = 409600
#define OFF_WP     1452800  // 65536 ushort = 32768 floats
// total 1485568 floats ~= 5.94 MB

typedef __attribute__((ext_vector_type(8))) short short8;
typedef __attribute__((ext_vector_type(4))) float f32x4;

__device__ __forceinline__ float silu_(float v) {
    return v * (1.0f / (1.0f + __expf(-v)));
}
__device__ __forceinline__ unsigned short f2bf(float f) {
    unsigned int u = __float_as_uint(f);
    unsigned int r = (u + 0x7fffu + ((u >> 16) & 1u)) >> 16;
    return (unsigned short)r;
}
__device__ __forceinline__ float bf2f(unsigned short v) {
    return __uint_as_float(((unsigned int)v) << 16);
}

// ================= fused setup: packW | edges | xinit | embed =================
#define PACK_BLKS_  256   // 65536 elems
#define EDGE_BLKS_  325   // 83200 elems
#define XI_BLKS_    32    // 8000 elems
#define EMB_BLKS_   8     // 2000 elems
#define SETUP_BLKS_ (PACK_BLKS_ + EDGE_BLKS_ + XI_BLKS_ + EMB_BLKS_)

__global__ __launch_bounds__(256) void k_setup(
    const float* __restrict__ x_h, const float* __restrict__ x_hv,
    const int* __restrict__ bound,
    const int* __restrict__ ehh, const float* __restrict__ em_hh,
    const float* __restrict__ em_hv, const float* __restrict__ bond,
    const float* __restrict__ W2, const float* __restrict__ Wc1,
    const int* __restrict__ lab_h, const int* __restrict__ pos_h,
    const int* __restrict__ lab_hv, const int* __restrict__ pos_hv,
    const int* __restrict__ pep,
    float* __restrict__ feat_h, float* __restrict__ feat_hv,
    float* __restrict__ x, float* __restrict__ x0h,
    int* __restrict__ erow, int* __restrict__ ecol,
    float* __restrict__ emk, float* __restrict__ ebd,
    unsigned short* __restrict__ Wp)
{
    int blk = blockIdx.x, t = threadIdx.x;
    if (blk < PACK_BLKS_) {
        // Wp[l][mat][((kc*128 + n)*4 + q)*8 + j] = bf16(W[l][kc*32+q*8+j][n])
        int g = blk*256 + t;
        int idx = g & 16383;
        int lm  = g >> 14;
        int l = lm >> 1, mat = lm & 1;
        int j = idx & 7, q = (idx >> 3) & 3, n = (idx >> 5) & 127, kc = idx >> 12;
        int k = kc*32 + q*8 + j;
        const float* W = (mat == 0 ? W2 : Wc1) + l*HID_*HID_;
        Wp[g] = f2bf(W[k*HID_ + n]);
        return;
    }
    blk -= PACK_BLKS_;
    if (blk < EDGE_BLKS_) {
        int g = blk*256 + t;                  // exactly 83200
        int b = g / NE_, e = g % NE_;
        int r, c; float em, bd;
        if (e < EHH_) {
            r = ehh[(b*EHH_ + e)*2 + 0];
            c = ehh[(b*EHH_ + e)*2 + 1];
            em = em_hh[b*EHH_ + e];
            bd = 0.0f;
        } else {
            int k = e - EHH_;
            r = k / NH_; int cc = k % NH_; c = H_ + cc;
            em = em_hv[(b*H_ + r)*NH_ + cc];
            bd = bond [(b*H_ + r)*NH_ + cc];
        }
        erow[g] = r; ecol[g] = c; emk[g] = em; ebd[g] = bd;
        return;
    }
    blk -= EDGE_BLKS_;
    if (blk < XI_BLKS_) {
        int g = blk*256 + t;
        if (g >= BS_*NN_) return;
        int bs = g / NN_, n = g % NN_;
        int b = bs / S_;
        if (n < H_) {
            int ba = bound[b*H_ + n];
            for (int d = 0; d < 3; ++d) {
                float v = x_h[(bs*H_ + n)*3 + d] + x_hv[(b*NH_ + ba)*3 + d];
                x[g*4 + d] = v;
                x0h[(bs*H_ + n)*4 + d] = v;
            }
        } else {
            int nh = n - H_;
            for (int d = 0; d < 3; ++d) x[g*4 + d] = x_hv[(b*NH_ + nh)*3 + d];
        }
        return;
    }
    blk -= XI_BLKS_;
    {
        int g = blk*256 + t;
        if (g >= B_*H_ + B_*NH_) return;      // 2000
        if (g < B_*H_) {
            int b = g / H_, h = g % H_;
            int label = lab_h[g], pos = pos_h[g];
            int aa = pep[b*15 + pos - 1];
            for (int f = 0; f < FDIM_; ++f) {
                float v;
                if (f < 44)      v = (f == label)          ? 1.0f : 0.0f;
                else if (f < 64) v = ((f - 44) == aa)      ? 1.0f : 0.0f;
                else             v = ((f - 64) == pos - 1) ? 1.0f : 0.0f;
                for (int s = 0; s < S_; ++s)
                    feat_h[(((b*S_ + s)*H_) + h)*FS_ + f] = v;
            }
        } else {
            int g2 = g - B_*H_;               // b*NH + nh
            int b = g2 / NH_;
            int label = lab_hv[g2], pos = pos_hv[g2];
            int aa = pep[b*15 + pos - 1];
            for (int f = 0; f < FDIM_; ++f) {
                float v;
                if (f < 44)      v = (f == label)          ? 1.0f : 0.0f;
                else if (f < 64) v = ((f - 44) == aa)      ? 1.0f : 0.0f;
                else             v = ((f - 64) == pos - 1) ? 1.0f : 0.0f;
                feat_hv[g2*FS_ + f] = v;
            }
        }
    }
}

// ============ per-layer: node @ W1 (batched, 16 nodes/block) + zero agg ============
// blocks [0,100):  h nodes   -> hiW1h[bs*H+h], hjW1all[bs*H+h]
// blocks [100,200): heavy    -> hjW1all[BS*H + b*NH+nh]
// blocks [200,300): zero aggx+aggm (211200 floats contiguous)
__global__ __launch_bounds__(128) void k_nodeW1(
    const float* __restrict__ feat_h, const float* __restrict__ feat_hv,
    const float* __restrict__ W1, int l,
    float* __restrict__ hiW1h, float* __restrict__ hjW1all,
    float* __restrict__ zbase)
{
    int blk = blockIdx.x, t = threadIdx.x;
    if (blk >= 200) {
        float4* z = (float4*)zbase;
        int base = (blk - 200) * 528;
        for (int i = t; i < 528; i += 128) {
            int idx = base + i;
            if (idx < 52800) z[idx] = make_float4(0.f, 0.f, 0.f, 0.f);
        }
        return;
    }
    __shared__ float sf[16][FS_];
    const float* W1l = W1 + l*EDIM_*HID_;
    if (blk < 100) {
        int node0 = blk * 16;                  // in [0,1600): bs*H+h
        for (int idx = t; idx < 16*FS_; idx += 128) {
            int g = idx / FS_, f = idx % FS_;
            sf[g][f] = feat_h[(node0 + g)*FS_ + f];
        }
        __syncthreads();
        float acci[16], accj[16];
        #pragma unroll
        for (int g = 0; g < 16; ++g) { acci[g] = 0.f; accj[g] = 0.f; }
        for (int f = 0; f < FDIM_; ++f) {
            float wi = W1l[f*HID_ + t];
            float wj = W1l[(FDIM_ + f)*HID_ + t];
            #pragma unroll
            for (int g = 0; g < 16; ++g) {
                float v = sf[g][f];
                acci[g] += v * wi;
                accj[g] += v * wj;
            }
        }
        #pragma unroll
        for (int g = 0; g < 16; ++g) {
            hiW1h [(node0 + g)*HID_ + t] = acci[g];
            hjW1all[(node0 + g)*HID_ + t] = accj[g];
        }
    } else {
        int node0 = (blk - 100) * 16;          // in [0,1600): b*NH+nh
        for (int idx = t; idx < 16*FS_; idx += 128) {
            int g = idx / FS_, f = idx % FS_;
            sf[g][f] = feat_hv[(node0 + g)*FS_ + f];
        }
        __syncthreads();
        float accj[16];
        #pragma unroll
        for (int g = 0; g < 16; ++g) accj[g] = 0.f;
        for (int f = 0; f < FDIM_; ++f) {
            float wj = W1l[(FDIM_ + f)*HID_ + t];
            #pragma unroll
            for (int g = 0; g < 16; ++g) accj[g] += sf[g][f] * wj;
        }
        #pragma unroll
        for (int g = 0; g < 16; ++g)
            hjW1all[(BS_*H_ + node0 + g)*HID_ + t] = accj[g];
    }
}

// ============ per-layer: fused MFMA edge MLP + segment aggregation ============
__global__ __launch_bounds__(256, 4) void k_edge_mlp(
    const float* __restrict__ x, const float* __restrict__ hiW1h,
    const float* __restrict__ hjW1all,
    const int* __restrict__ erow, const int* __restrict__ ecol,
    const float* __restrict__ emk, const float* __restrict__ ebd,
    const float* __restrict__ t_in,
    const float* __restrict__ W1, const float* __restrict__ b1,
    const float* __restrict__ b2, const float* __restrict__ bc1,
    const float* __restrict__ Wc2,
    const unsigned short* __restrict__ Wp, int l,
    float* __restrict__ aggx, float* __restrict__ aggm)
{
    __shared__ unsigned short s_m[TE_][MSTR_];   // 17408 B : bf16 m tile
    __shared__ float s_partT[16][68];            // 4352 B  : cw partials, transposed
    __shared__ float s_diff[TE_][4];
    __shared__ float s_db  [TE_][2];             // dist, bond
    __shared__ float s_emk [TE_];
    __shared__ float s_tb  [TE_];
    __shared__ int   s_ii  [TE_];                // bs*H + row
    __shared__ int   s_jj  [TE_];                // combined hjW1all row index

    const int t = threadIdx.x;
    const int lane = t & 63, w = t >> 6;
    const int l15 = lane & 15, q = lane >> 4;

    // ---- setup: per-edge scalars ----
    if (t < TE_) {
        int ge = blockIdx.x*TE_ + t;
        int bs = ge / NE_;
        int e  = ge - bs*NE_;
        int b  = bs / S_;
        int row = erow[b*NE_ + e], col = ecol[b*NE_ + e];
        s_ii[t] = bs*H_ + row;
        s_jj[t] = (col < H_) ? (bs*H_ + col) : (BS_*H_ + b*NH_ + (col - H_));
        float dx0 = x[(bs*NN_ + row)*4 + 0] - x[(bs*NN_ + col)*4 + 0];
        float dx1 = x[(bs*NN_ + row)*4 + 1] - x[(bs*NN_ + col)*4 + 1];
        float dx2 = x[(bs*NN_ + row)*4 + 2] - x[(bs*NN_ + col)*4 + 2];
        s_diff[t][0] = dx0; s_diff[t][1] = dx1; s_diff[t][2] = dx2;
        s_db[t][0] = sqrtf(dx0*dx0 + dx1*dx1 + dx2*dx2);
        s_db[t][1] = ebd[b*NE_ + e];
        s_emk[t]   = emk[b*NE_ + e];
        s_tb[t]    = t_in[b];
    }
    __syncthreads();

    const int mrow = w*16 + l15;   // this lane's A-row (edge) for MFMA

    // ---- stage 1 (register-direct): afrag[kc] = bf16 m1[mrow][kc*32+q*8 .. +8] ----
    short8 afrag[4];
    {
        const float* W1l = W1 + l*EDIM_*HID_;
        const float* b1l = b1 + l*HID_;
        int ri = s_ii[mrow], rj = s_jj[mrow];
        float dist = s_db[mrow][0], bond = s_db[mrow][1], tb = s_tb[mrow];
        const float* pi = hiW1h  + (size_t)ri*HID_ + q*8;
        const float* pj = hjW1all + (size_t)rj*HID_ + q*8;
        #pragma unroll
        for (int kc = 0; kc < 4; ++kc) {
            int k0 = kc*32 + q*8;
            float4 a0 = *(const float4*)(pi + kc*32);
            float4 a1 = *(const float4*)(pi + kc*32 + 4);
            float4 c0 = *(const float4*)(pj + kc*32);
            float4 c1 = *(const float4*)(pj + kc*32 + 4);
            float4 wa0 = *(const float4*)(W1l + 158*HID_ + k0);
            float4 wa1 = *(const float4*)(W1l + 158*HID_ + k0 + 4);
            float4 wb0 = *(const float4*)(W1l + 159*HID_ + k0);
            float4 wb1 = *(const float4*)(W1l + 159*HID_ + k0 + 4);
            float4 wc0 = *(const float4*)(W1l + 160*HID_ + k0);
            float4 wc1 = *(const float4*)(W1l + 160*HID_ + k0 + 4);
            float4 bb0 = *(const float4*)(b1l + k0);
            float4 bb1 = *(const float4*)(b1l + k0 + 4);
            short8 fr;
            fr[0] = (short)f2bf(silu_(a0.x + c0.x + dist*wa0.x + bond*wb0.x + tb*wc0.x + bb0.x));
            fr[1] = (short)f2bf(silu_(a0.y + c0.y + dist*wa0.y + bond*wb0.y + tb*wc0.y + bb0.y));
            fr[2] = (short)f2bf(silu_(a0.z + c0.z + dist*wa0.z + bond*wb0.z + tb*wc0.z + bb0.z));
            fr[3] = (short)f2bf(silu_(a0.w + c0.w + dist*wa0.w + bond*wb0.w + tb*wc0.w + bb0.w));
            fr[4] = (short)f2bf(silu_(a1.x + c1.x + dist*wa1.x + bond*wb1.x + tb*wc1.x + bb1.x));
            fr[5] = (short)f2bf(silu_(a1.y + c1.y + dist*wa1.y + bond*wb1.y + tb*wc1.y + bb1.y));
            fr[6] = (short)f2bf(silu_(a1.z + c1.z + dist*wa1.z + bond*wb1.z + tb*wc1.z + bb1.z));
            fr[7] = (short)f2bf(silu_(a1.w + c1.w + dist*wa1.w + bond*wb1.w + tb*wc1.w + bb1.w));
            afrag[kc] = fr;
        }
    }

    // ---- stage 2: m = silu(m1 @ W2 + b2) * emask  (MFMA, wave-private rows) ----
    {
        const unsigned short* Wp2 = Wp + (size_t)(l*2 + 0)*16384;
        const float* b2l = b2 + l*HID_;
        float em4[4];
        #pragma unroll
        for (int r = 0; r < 4; ++r) em4[r] = s_emk[w*16 + q*4 + r];
        f32x4 acc[8];
        #pragma unroll
        for (int nt = 0; nt < 8; ++nt) {
            f32x4 c = {0.f, 0.f, 0.f, 0.f};
            #pragma unroll
            for (int kc = 0; kc < 4; ++kc) {
                short8 bfrag = *(const short8*)&Wp2[((kc*128 + nt*16 + l15)*4 + q)*8];
                c = __builtin_amdgcn_mfma_f32_16x16x32_bf16(afrag[kc], bfrag, c, 0, 0, 0);
            }
            acc[nt] = c;
        }
        #pragma unroll
        for (int nt = 0; nt < 8; ++nt) {
            int colj = nt*16 + l15;
            float bias = b2l[colj];
            #pragma unroll
            for (int r = 0; r < 4; ++r) {
                int rowe = w*16 + q*4 + r;     // wave-private row
                s_m[rowe][colj] = f2bf(silu_(acc[nt][r] + bias) * em4[r]);
            }
        }
    }
    __builtin_amdgcn_wave_barrier();   // keep ds_write (above) before ds_read (below)

    // ---- stage 3: cw = silu(m @ Wc1 + bc1) @ Wc2  (MFMA, wave-private rows) ----
    {
        short8 af2[4];
        #pragma unroll
        for (int kc = 0; kc < 4; ++kc)
            af2[kc] = *(const short8*)&s_m[mrow][kc*32 + q*8];
        const unsigned short* Wp3 = Wp + (size_t)(l*2 + 1)*16384;
        f32x4 acc[8];
        #pragma unroll
        for (int nt = 0; nt < 8; ++nt) {
            f32x4 c = {0.f, 0.f, 0.f, 0.f};
            #pragma unroll
            for (int kc = 0; kc < 4; ++kc) {
                short8 bfrag = *(const short8*)&Wp3[((kc*128 + nt*16 + l15)*4 + q)*8];
                c = __builtin_amdgcn_mfma_f32_16x16x32_bf16(af2[kc], bfrag, c, 0, 0, 0);
            }
            acc[nt] = c;
        }
        const float* bc1l = bc1 + l*HID_;
        const float* wc2l = Wc2 + l*HID_;
        float p[4] = {0.f, 0.f, 0.f, 0.f};
        #pragma unroll
        for (int nt = 0; nt < 8; ++nt) {
            int colj = nt*16 + l15;
            float bias = bc1l[colj];
            float wcv  = wc2l[colj];
            #pragma unroll
            for (int r = 0; r < 4; ++r)
                p[r] += silu_(acc[nt][r] + bias) * wcv;
        }
        // transposed partials: one b128 per lane, conflict-light
        *(float4*)&s_partT[l15][w*16 + q*4] = make_float4(p[0], p[1], p[2], p[3]);
    }
    __syncthreads();

    // ---- wave 0: cw reduce + aggx (shuffle, no extra barrier) ----
    if (t < TE_) {
        float cwv = 0.f;
        #pragma unroll
        for (int c = 0; c < 16; ++c) cwv += s_partT[c][t];
        float run = 0.f; int ct = s_ii[0];
        int d = lane & 3;                       // lanes 0..2 meaningful
        for (int i2 = 0; i2 < TE_; ++i2) {
            float cwi = __shfl(cwv, i2, 64);
            int tg = s_ii[i2];
            if (tg != ct) {
                if (lane < 3) atomicAdd(&aggx[(size_t)ct*4 + d], run);
                run = 0.f; ct = tg;
            }
            run += s_diff[i2][d] * cwi;
        }
        if (lane < 3) atomicAdd(&aggx[(size_t)ct*4 + d], run);
    } else if (t < TE_ + HID_) {
        // ---- waves 1,2: aggm run-length compressed column sums ----
        int j = t - TE_;
        float run = 0.f; int ct = s_ii[0];
        for (int i2 = 0; i2 < TE_; ++i2) {
            int tg = s_ii[i2];
            if (tg != ct) {
                atomicAdd(&aggm[(size_t)ct*HID_ + j], run);
                run = 0.f; ct = tg;
            }
            run += bf2f(s_m[i2][j]);
        }
        atomicAdd(&aggm[(size_t)ct*HID_ + j], run);
    }
}

// ============ per-layer: node update (batched, 8 nodes/block; fuses output) ============
__global__ __launch_bounds__(128) void k_node_update(
    float* __restrict__ feat_h, float* __restrict__ x,
    const float* __restrict__ aggm, const float* __restrict__ aggx,
    const float* __restrict__ Wn1, const float* __restrict__ bn1,
    const float* __restrict__ Wn2, const float* __restrict__ bn2, int l,
    const float* __restrict__ x0h, const float* __restrict__ amask,
    float* __restrict__ out)
{
    __shared__ float s_in[8][NDIM_ + 1];   // 208
    __shared__ float s_u[8][HID_ + 1];
    int node0 = blockIdx.x * 8;            // bs*H + h
    int t = threadIdx.x;
    for (int idx = t; idx < 8*(NDIM_ + 1); idx += 128) {
        int g = idx / (NDIM_ + 1), k = idx % (NDIM_ + 1);
        float v = 0.f;
        if (k < FDIM_)      v = feat_h[(node0 + g)*FS_ + k];
        else if (k < NDIM_) v = aggm[(size_t)(node0 + g)*HID_ + (k - FDIM_)];
        s_in[g][k] = v;
    }
    __syncthreads();
    const float* Wn1l = Wn1 + l*NDIM_*HID_;
    float acc[8];
    float bv = bn1[l*HID_ + t];
    #pragma unroll
    for (int g = 0; g < 8; ++g) acc[g] = bv;
    for (int k = 0; k < NDIM_; ++k) {
        float wv = Wn1l[k*HID_ + t];
        #pragma unroll
        for (int g = 0; g < 8; ++g) acc[g] += s_in[g][k] * wv;
    }
    #pragma unroll
    for (int g = 0; g < 8; ++g) s_u[g][t] = silu_(acc[g]);
    __syncthreads();
    if (t < FDIM_) {
        const float* Wn2l = Wn2 + l*HID_*FDIM_;
        float acc2[8];
        float b2v = bn2[l*FDIM_ + t];
        #pragma unroll
        for (int g = 0; g < 8; ++g) acc2[g] = b2v;
        for (int k = 0; k < HID_; ++k) {
            float wv = Wn2l[k*FDIM_ + t];
            #pragma unroll
            for (int g = 0; g < 8; ++g) acc2[g] += s_u[g][k] * wv;
        }
        #pragma unroll
        for (int g = 0; g < 8; ++g)
            feat_h[(node0 + g)*FS_ + t] = s_in[g][t] + acc2[g];
    } else if (t >= 96 && t < 120) {
        int idx = t - 96, g = idx / 3, d = idx % 3;
        int node = node0 + g;
        int bs = node / H_, h = node % H_;
        float xv = x[(bs*NN_ + h)*4 + d] + aggx[node*4 + d];
        x[(bs*NN_ + h)*4 + d] = xv;
        if (l == L_ - 1) {
            int b = bs / S_;
            out[node*3 + d] = (xv - x0h[node*4 + d]) * amask[b*H_ + h];
        }
    }
}

// ---------------- launch ----------------
extern "C" void kernel_launch(void* const* d_in, const int* in_sizes, int n_in,
                              void* d_out, int out_size, void* d_ws, size_t ws_size,
                              hipStream_t stream)
{
    const float* t_in  = (const float*)d_in[0];
    const float* x_h   = (const float*)d_in[1];
    const float* x_hv  = (const float*)d_in[2];
    const float* bond  = (const float*)d_in[3];
    const float* em_hv = (const float*)d_in[4];
    const float* em_hh = (const float*)d_in[5];
    const float* amask = (const float*)d_in[6];
    const float* W1    = (const float*)d_in[7];
    const float* b1    = (const float*)d_in[8];
    const float* W2    = (const float*)d_in[9];
    const float* b2    = (const float*)d_in[10];
    const float* Wc1   = (const float*)d_in[11];
    const float* bc1   = (const float*)d_in[12];
    const float* Wc2   = (const float*)d_in[13];
    const float* Wn1   = (const float*)d_in[14];
    const float* bn1   = (const float*)d_in[15];
    const float* Wn2   = (const float*)d_in[16];
    const float* bn2   = (const float*)d_in[17];
    const int* pep     = (const int*)d_in[18];
    const int* lab_hv  = (const int*)d_in[19];
    const int* lab_h   = (const int*)d_in[20];
    const int* pos_hv  = (const int*)d_in[21];
    const int* pos_h   = (const int*)d_in[22];
    const int* ehh     = (const int*)d_in[23];
    const int* bound   = (const int*)d_in[24];

    float* ws     = (float*)d_ws;
    float* feat_h = ws + OFF_FEATH;
    float* feat_hv= ws + OFF_FEATHV;
    float* x      = ws + OFF_X;
    float* x0h    = ws + OFF_X0H;
    int*   erow   = (int*)(ws + OFF_EROW);
    int*   ecol   = (int*)(ws + OFF_ECOL);
    float* emk    = ws + OFF_EMASK;
    float* ebd    = ws + OFF_EBOND;
    float* aggx   = ws + OFF_AGGX;
    float* aggm   = ws + OFF_AGGM;
    float* hiW1h  = ws + OFF_HIW1;
    float* hjW1a  = ws + OFF_HJW1;
    unsigned short* Wp = (unsigned short*)(ws + OFF_WP);

    hipLaunchKernelGGL(k_setup, dim3(SETUP_BLKS_), dim3(256), 0, stream,
                       x_h, x_hv, bound, ehh, em_hh, em_hv, bond, W2, Wc1,
                       lab_h, pos_h, lab_hv, pos_hv, pep,
                       feat_h, feat_hv, x, x0h, erow, ecol, emk, ebd, Wp);

    for (int l = 0; l < L_; ++l) {
        hipLaunchKernelGGL(k_nodeW1, dim3(300), dim3(128), 0, stream,
                           feat_h, feat_hv, W1, l, hiW1h, hjW1a, aggx /*zbase*/);
        hipLaunchKernelGGL(k_edge_mlp, dim3(TOTE_/TE_), dim3(256), 0, stream,
                           x, hiW1h, hjW1a, erow, ecol, emk, ebd, t_in,
                           W1, b1, b2, bc1, Wc2, Wp, l, aggx, aggm);
        hipLaunchKernelGGL(k_node_update, dim3(200), dim3(128), 0, stream,
                           feat_h, x, aggm, aggx, Wn1, bn1, Wn2, bn2, l,
                           x0h, amask, (float*)d_out);
    }
}

// Round 4
// 485.558 us; speedup vs baseline: 10.2134x; 1.1816x over previous
//
#include <hip/hip_runtime.h>
#include <math.h>

// Problem constants
#define B_     8
#define S_     4
#define H_     50
#define NH_    200
#define EHH_   400
#define L_     2
#define HID_   128
#define FDIM_  79          // 44 + 20 + 15
#define EDIM_  161         // 2*FDIM + 3
#define NN_    250         // H + NH
#define NE_    10400       // EHH + H*NH
#define BS_    32          // B*S
#define TOTE_  (BS_*NE_)   // 332800
#define FS_    80          // feat row stride
#define TE_    64          // edges per block in edge kernel
#define MSTR_  136         // s_m stride in bf16 (128 + 8)
#define NDIM_  207         // FDIM + HID

// Workspace layout (float offsets)
#define OFF_FEATH  0         // BS*H*80 = 128000 (fp32 h-node features, layer-current)
#define OFF_X      128000    // BS*NN*4 = 32000
#define OFF_X0H    160000    // BS*H*4  = 6400
#define OFF_EROW   166400    // 83200 (int)
#define OFF_ECOL   249600    // 83200 (int)
#define OFF_EMASK  332800    // 83200
#define OFF_EBOND  416000    // 83200
#define OFF_AGG0   499200    // aggx0(6400) + aggm0(204800) = 211200
#define OFF_AGG1   710400    // aggx1(6400) + aggm1(204800) = 211200
#define OFF_HIW1   921600    // fp32 1600*128 = 204800 (layer-current h rows)
#define OFF_HJW1   1126400   // fp32 4800*128 = 614400: [0,1600) h cur | [1600,3200) hv l0 | [3200,4800) hv l1
#define OFF_WP     1740800   // 65536 ushort = 32768 floats
// total ~1773568 floats ~= 7.1 MB
#define AGGSTRIDE_ 211200

typedef __attribute__((ext_vector_type(8))) short short8;
typedef __attribute__((ext_vector_type(4))) float f32x4;

__device__ __forceinline__ float silu_(float v) {
    return v * (1.0f / (1.0f + __expf(-v)));
}
__device__ __forceinline__ unsigned short f2bf(float f) {
    unsigned int u = __float_as_uint(f);
    unsigned int r = (u + 0x7fffu + ((u >> 16) & 1u)) >> 16;
    return (unsigned short)r;
}
__device__ __forceinline__ float bf2f(unsigned short v) {
    return __uint_as_float(((unsigned int)v) << 16);
}

// ================= fused setup =================
// phases (block ranges): heavy hjW1 both layers | packW | edges | h one-hot W1 l0 |
//                        feat_h l0 | zero agg0 | xinit
#define HV_BLKS_    1600   // 2*1600*128 = 409600
#define PACK_BLKS_  256    // 65536
#define EDGE_BLKS_  325    // 83200
#define HROW_BLKS_  200    // 400*128 = 51200
#define FEAT_BLKS_  125    // 400*80 = 32000
#define ZERO_BLKS_  207    // 52800 float4
#define XI_BLKS_    32     // 8000
#define SETUP_BLKS_ (HV_BLKS_ + PACK_BLKS_ + EDGE_BLKS_ + HROW_BLKS_ + FEAT_BLKS_ + ZERO_BLKS_ + XI_BLKS_)

__global__ __launch_bounds__(256) void k_setup(
    const float* __restrict__ x_h, const float* __restrict__ x_hv,
    const int* __restrict__ bound,
    const int* __restrict__ ehh, const float* __restrict__ em_hh,
    const float* __restrict__ em_hv, const float* __restrict__ bond,
    const float* __restrict__ W1, const float* __restrict__ W2,
    const float* __restrict__ Wc1,
    const int* __restrict__ lab_h, const int* __restrict__ pos_h,
    const int* __restrict__ lab_hv, const int* __restrict__ pos_hv,
    const int* __restrict__ pep,
    float* __restrict__ feat_h,
    float* __restrict__ x, float* __restrict__ x0h,
    int* __restrict__ erow, int* __restrict__ ecol,
    float* __restrict__ emk, float* __restrict__ ebd,
    float* __restrict__ hiW1, float* __restrict__ hjW1,
    float* __restrict__ agg0,
    unsigned short* __restrict__ Wp)
{
    int blk = blockIdx.x, t = threadIdx.x;
    if (blk < HV_BLKS_) {
        // heavy-node hjW1 = sum of 3 rows of W1 (one-hot features), per layer
        int g = blk*256 + t;                 // [0, 409600)
        int l = g / 204800;
        int r = g - l*204800;
        int node = r >> 7, col = r & 127;    // node = b*NH + nh
        int b = node / NH_;
        int label = lab_hv[node], pos = pos_hv[node];
        int aa = pep[b*15 + pos - 1];
        const float* W1l = W1 + l*EDIM_*HID_;
        float hj = W1l[(FDIM_ + label)*HID_ + col]
                 + W1l[(FDIM_ + 44 + aa)*HID_ + col]
                 + W1l[(FDIM_ + 64 + pos - 1)*HID_ + col];
        hjW1[(size_t)(1600 + l*1600 + node)*HID_ + col] = hj;
        return;
    }
    blk -= HV_BLKS_;
    if (blk < PACK_BLKS_) {
        // Wp[l][mat][((kc*128 + n)*4 + q)*8 + j] = bf16(W[l][kc*32+q*8+j][n])
        int g = blk*256 + t;
        int idx = g & 16383;
        int lm  = g >> 14;
        int l = lm >> 1, mat = lm & 1;
        int j = idx & 7, q = (idx >> 3) & 3, n = (idx >> 5) & 127, kc = idx >> 12;
        int k = kc*32 + q*8 + j;
        const float* W = (mat == 0 ? W2 : Wc1) + l*HID_*HID_;
        Wp[g] = f2bf(W[k*HID_ + n]);
        return;
    }
    blk -= PACK_BLKS_;
    if (blk < EDGE_BLKS_) {
        int g = blk*256 + t;                  // exactly 83200
        int b = g / NE_, e = g % NE_;
        int r, c; float em, bd;
        if (e < EHH_) {
            r = ehh[(b*EHH_ + e)*2 + 0];
            c = ehh[(b*EHH_ + e)*2 + 1];
            em = em_hh[b*EHH_ + e];
            bd = 0.0f;
        } else {
            int k = e - EHH_;
            r = k / NH_; int cc = k % NH_; c = H_ + cc;
            em = em_hv[(b*H_ + r)*NH_ + cc];
            bd = bond [(b*H_ + r)*NH_ + cc];
        }
        erow[g] = r; ecol[g] = c; emk[g] = em; ebd[g] = bd;
        return;
    }
    blk -= EDGE_BLKS_;
    if (blk < HROW_BLKS_) {
        // h-node hiW1/hjW1 for layer 0 (one-hot): per (b,h), replicate over s
        int g = blk*256 + t;                 // [0, 51200)
        int node = g >> 7, col = g & 127;    // node = b*H + h
        int b = node / H_, h = node % H_;
        int label = lab_h[node], pos = pos_h[node];
        int aa = pep[b*15 + pos - 1];
        const float* W1l = W1;               // layer 0
        float hi = W1l[label*HID_ + col]
                 + W1l[(44 + aa)*HID_ + col]
                 + W1l[(64 + pos - 1)*HID_ + col];
        float hj = W1l[(FDIM_ + label)*HID_ + col]
                 + W1l[(FDIM_ + 44 + aa)*HID_ + col]
                 + W1l[(FDIM_ + 64 + pos - 1)*HID_ + col];
        #pragma unroll
        for (int s = 0; s < S_; ++s) {
            int row = (b*S_ + s)*H_ + h;
            hiW1[(size_t)row*HID_ + col] = hi;
            hjW1[(size_t)row*HID_ + col] = hj;
        }
        return;
    }
    blk -= HROW_BLKS_;
    if (blk < FEAT_BLKS_) {
        // fp32 one-hot h features (layer 0) for node_update input
        int g = blk*256 + t;                 // [0, 32000)
        int node = g / FS_, f = g % FS_;     // node = b*H + h
        int b = node / H_, h = node % H_;
        int label = lab_h[node], pos = pos_h[node];
        int aa = pep[b*15 + pos - 1];
        float v = 0.f;
        if (f < 44)      v = (f == label)          ? 1.0f : 0.0f;
        else if (f < 64) v = ((f - 44) == aa)      ? 1.0f : 0.0f;
        else if (f < 79) v = ((f - 64) == pos - 1) ? 1.0f : 0.0f;
        #pragma unroll
        for (int s = 0; s < S_; ++s)
            feat_h[((b*S_ + s)*H_ + h)*FS_ + f] = v;
        return;
    }
    blk -= FEAT_BLKS_;
    if (blk < ZERO_BLKS_) {
        int idx = blk*256 + t;
        if (idx < 52800) ((float4*)agg0)[idx] = make_float4(0.f, 0.f, 0.f, 0.f);
        return;
    }
    blk -= ZERO_BLKS_;
    {
        int g = blk*256 + t;
        if (g >= BS_*NN_) return;
        int bs = g / NN_, n = g % NN_;
        int b = bs / S_;
        if (n < H_) {
            int ba = bound[b*H_ + n];
            for (int d = 0; d < 3; ++d) {
                float v = x_h[(bs*H_ + n)*3 + d] + x_hv[(b*NH_ + ba)*3 + d];
                x[g*4 + d] = v;
                x0h[(bs*H_ + n)*4 + d] = v;
            }
        } else {
            int nh = n - H_;
            for (int d = 0; d < 3; ++d) x[g*4 + d] = x_hv[(b*NH_ + nh)*3 + d];
        }
    }
}

// ============ per-layer: fused MFMA edge MLP + segment aggregation ============
__global__ __launch_bounds__(256, 4) void k_edge_mlp(
    const float* __restrict__ x, const float* __restrict__ hiW1,
    const float* __restrict__ hjW1,
    const int* __restrict__ erow, const int* __restrict__ ecol,
    const float* __restrict__ emk, const float* __restrict__ ebd,
    const float* __restrict__ t_in,
    const float* __restrict__ W1, const float* __restrict__ b1,
    const float* __restrict__ b2, const float* __restrict__ bc1,
    const float* __restrict__ Wc2,
    const unsigned short* __restrict__ Wp, int l,
    float* __restrict__ aggx, float* __restrict__ aggm)
{
    __shared__ unsigned short s_m[TE_][MSTR_];   // 17408 B : bf16 m tile
    __shared__ float s_partT[16][68];            // 4352 B  : cw partials, transposed
    __shared__ float s_diff[TE_][4];
    __shared__ float s_db  [TE_][2];             // dist, bond
    __shared__ float s_emk [TE_];
    __shared__ float s_tb  [TE_];
    __shared__ int   s_ii  [TE_];                // bs*H + row
    __shared__ int   s_jj  [TE_];                // hjW1 row index

    const int t = threadIdx.x;
    const int lane = t & 63, w = t >> 6;
    const int l15 = lane & 15, q = lane >> 4;

    // ---- setup: per-edge scalars ----
    if (t < TE_) {
        int ge = blockIdx.x*TE_ + t;
        int bs = ge / NE_;
        int e  = ge - bs*NE_;
        int b  = bs / S_;
        int row = erow[b*NE_ + e], col = ecol[b*NE_ + e];
        s_ii[t] = bs*H_ + row;
        s_jj[t] = (col < H_) ? (bs*H_ + col) : (1600 + l*1600 + b*NH_ + (col - H_));
        float dx0 = x[(bs*NN_ + row)*4 + 0] - x[(bs*NN_ + col)*4 + 0];
        float dx1 = x[(bs*NN_ + row)*4 + 1] - x[(bs*NN_ + col)*4 + 1];
        float dx2 = x[(bs*NN_ + row)*4 + 2] - x[(bs*NN_ + col)*4 + 2];
        s_diff[t][0] = dx0; s_diff[t][1] = dx1; s_diff[t][2] = dx2;
        s_db[t][0] = sqrtf(dx0*dx0 + dx1*dx1 + dx2*dx2);
        s_db[t][1] = ebd[b*NE_ + e];
        s_emk[t]   = emk[b*NE_ + e];
        s_tb[t]    = t_in[b];
    }
    __syncthreads();

    const int mrow = w*16 + l15;   // this lane's A-row (edge) for MFMA

    // ---- stage 1 (register-direct): afrag[kc] = bf16 m1[mrow][kc*32+q*8 .. +8] ----
    short8 afrag[4];
    {
        const float* W1l = W1 + l*EDIM_*HID_;
        const float* b1l = b1 + l*HID_;
        int ri = s_ii[mrow], rj = s_jj[mrow];
        float dist = s_db[mrow][0], bond = s_db[mrow][1], tb = s_tb[mrow];
        const float* pi = hiW1 + (size_t)ri*HID_ + q*8;
        const float* pj = hjW1 + (size_t)rj*HID_ + q*8;
        #pragma unroll
        for (int kc = 0; kc < 4; ++kc) {
            int k0 = kc*32 + q*8;
            float4 a0 = *(const float4*)(pi + kc*32);
            float4 a1 = *(const float4*)(pi + kc*32 + 4);
            float4 c0 = *(const float4*)(pj + kc*32);
            float4 c1 = *(const float4*)(pj + kc*32 + 4);
            float4 wa0 = *(const float4*)(W1l + 158*HID_ + k0);
            float4 wa1 = *(const float4*)(W1l + 158*HID_ + k0 + 4);
            float4 wb0 = *(const float4*)(W1l + 159*HID_ + k0);
            float4 wb1 = *(const float4*)(W1l + 159*HID_ + k0 + 4);
            float4 wc0 = *(const float4*)(W1l + 160*HID_ + k0);
            float4 wc1 = *(const float4*)(W1l + 160*HID_ + k0 + 4);
            float4 bb0 = *(const float4*)(b1l + k0);
            float4 bb1 = *(const float4*)(b1l + k0 + 4);
            short8 fr;
            fr[0] = (short)f2bf(silu_(a0.x + c0.x + dist*wa0.x + bond*wb0.x + tb*wc0.x + bb0.x));
            fr[1] = (short)f2bf(silu_(a0.y + c0.y + dist*wa0.y + bond*wb0.y + tb*wc0.y + bb0.y));
            fr[2] = (short)f2bf(silu_(a0.z + c0.z + dist*wa0.z + bond*wb0.z + tb*wc0.z + bb0.z));
            fr[3] = (short)f2bf(silu_(a0.w + c0.w + dist*wa0.w + bond*wb0.w + tb*wc0.w + bb0.w));
            fr[4] = (short)f2bf(silu_(a1.x + c1.x + dist*wa1.x + bond*wb1.x + tb*wc1.x + bb1.x));
            fr[5] = (short)f2bf(silu_(a1.y + c1.y + dist*wa1.y + bond*wb1.y + tb*wc1.y + bb1.y));
            fr[6] = (short)f2bf(silu_(a1.z + c1.z + dist*wa1.z + bond*wb1.z + tb*wc1.z + bb1.z));
            fr[7] = (short)f2bf(silu_(a1.w + c1.w + dist*wa1.w + bond*wb1.w + tb*wc1.w + bb1.w));
            afrag[kc] = fr;
        }
    }

    // ---- stage 2: m = silu(m1 @ W2 + b2) * emask  (MFMA, wave-private rows) ----
    {
        const unsigned short* Wp2 = Wp + (size_t)(l*2 + 0)*16384;
        const float* b2l = b2 + l*HID_;
        float em4[4];
        #pragma unroll
        for (int r = 0; r < 4; ++r) em4[r] = s_emk[w*16 + q*4 + r];
        f32x4 acc[8];
        #pragma unroll
        for (int nt = 0; nt < 8; ++nt) {
            f32x4 c = {0.f, 0.f, 0.f, 0.f};
            #pragma unroll
            for (int kc = 0; kc < 4; ++kc) {
                short8 bfrag = *(const short8*)&Wp2[((kc*128 + nt*16 + l15)*4 + q)*8];
                c = __builtin_amdgcn_mfma_f32_16x16x32_bf16(afrag[kc], bfrag, c, 0, 0, 0);
            }
            acc[nt] = c;
        }
        #pragma unroll
        for (int nt = 0; nt < 8; ++nt) {
            int colj = nt*16 + l15;
            float bias = b2l[colj];
            #pragma unroll
            for (int r = 0; r < 4; ++r) {
                int rowe = w*16 + q*4 + r;     // wave-private row
                s_m[rowe][colj] = f2bf(silu_(acc[nt][r] + bias) * em4[r]);
            }
        }
    }
    __builtin_amdgcn_wave_barrier();   // keep ds_write (above) before ds_read (below)

    // ---- stage 3: cw = silu(m @ Wc1 + bc1) @ Wc2  (MFMA, wave-private rows) ----
    {
        short8 af2[4];
        #pragma unroll
        for (int kc = 0; kc < 4; ++kc)
            af2[kc] = *(const short8*)&s_m[mrow][kc*32 + q*8];
        const unsigned short* Wp3 = Wp + (size_t)(l*2 + 1)*16384;
        f32x4 acc[8];
        #pragma unroll
        for (int nt = 0; nt < 8; ++nt) {
            f32x4 c = {0.f, 0.f, 0.f, 0.f};
            #pragma unroll
            for (int kc = 0; kc < 4; ++kc) {
                short8 bfrag = *(const short8*)&Wp3[((kc*128 + nt*16 + l15)*4 + q)*8];
                c = __builtin_amdgcn_mfma_f32_16x16x32_bf16(af2[kc], bfrag, c, 0, 0, 0);
            }
            acc[nt] = c;
        }
        const float* bc1l = bc1 + l*HID_;
        const float* wc2l = Wc2 + l*HID_;
        float p[4] = {0.f, 0.f, 0.f, 0.f};
        #pragma unroll
        for (int nt = 0; nt < 8; ++nt) {
            int colj = nt*16 + l15;
            float bias = bc1l[colj];
            float wcv  = wc2l[colj];
            #pragma unroll
            for (int r = 0; r < 4; ++r)
                p[r] += silu_(acc[nt][r] + bias) * wcv;
        }
        *(float4*)&s_partT[l15][w*16 + q*4] = make_float4(p[0], p[1], p[2], p[3]);
    }
    __syncthreads();

    // ---- wave 0: cw reduce + aggx (shuffle) ----
    if (t < TE_) {
        float cwv = 0.f;
        #pragma unroll
        for (int c = 0; c < 16; ++c) cwv += s_partT[c][t];
        float run = 0.f; int ct = s_ii[0];
        int d = lane & 3;                       // lanes 0..2 meaningful
        for (int i2 = 0; i2 < TE_; ++i2) {
            float cwi = __shfl(cwv, i2, 64);
            int tg = s_ii[i2];
            if (tg != ct) {
                if (lane < 3) atomicAdd(&aggx[(size_t)ct*4 + d], run);
                run = 0.f; ct = tg;
            }
            run += s_diff[i2][d] * cwi;
        }
        if (lane < 3) atomicAdd(&aggx[(size_t)ct*4 + d], run);
    } else if (t < TE_ + HID_) {
        // ---- waves 1,2: aggm run-length compressed column sums ----
        int j = t - TE_;
        float run = 0.f; int ct = s_ii[0];
        for (int i2 = 0; i2 < TE_; ++i2) {
            int tg = s_ii[i2];
            if (tg != ct) {
                atomicAdd(&aggm[(size_t)ct*HID_ + j], run);
                run = 0.f; ct = tg;
            }
            run += bf2f(s_m[i2][j]);
        }
        atomicAdd(&aggm[(size_t)ct*HID_ + j], run);
    }
}

// ====== per-layer: node update (8 nodes/block) + optional next-layer W1 + out ======
// grid: 200 blocks (+207 zero blocks when do_w1)
__global__ __launch_bounds__(128) void k_update(
    float* __restrict__ feat_h, float* __restrict__ x,
    const float* __restrict__ aggm, const float* __restrict__ aggx,
    const float* __restrict__ Wn1, const float* __restrict__ bn1,
    const float* __restrict__ Wn2, const float* __restrict__ bn2, int l,
    const float* __restrict__ W1,
    float* __restrict__ hiW1, float* __restrict__ hjW1,
    float* __restrict__ zbase, int do_w1,
    const float* __restrict__ x0h, const float* __restrict__ amask,
    float* __restrict__ out)
{
    if (blockIdx.x >= 200) {
        // zero next layer's agg buffers
        int z = blockIdx.x - 200;
        for (int idx = z*128 + threadIdx.x; idx < 52800; idx += 207*128)
            ((float4*)zbase)[idx] = make_float4(0.f, 0.f, 0.f, 0.f);
        return;
    }
    __shared__ float s_in[8][NDIM_ + 1];   // 208
    __shared__ float s_u[8][HID_ + 1];
    int node0 = blockIdx.x * 8;            // bs*H + h
    int t = threadIdx.x;
    for (int idx = t; idx < 8*(NDIM_ + 1); idx += 128) {
        int g = idx / (NDIM_ + 1), k = idx % (NDIM_ + 1);
        float v = 0.f;
        if (k < FDIM_)      v = feat_h[(node0 + g)*FS_ + k];
        else if (k < NDIM_) v = aggm[(size_t)(node0 + g)*HID_ + (k - FDIM_)];
        s_in[g][k] = v;
    }
    __syncthreads();
    const float* Wn1l = Wn1 + l*NDIM_*HID_;
    float acc[8];
    float bv = bn1[l*HID_ + t];
    #pragma unroll
    for (int g = 0; g < 8; ++g) acc[g] = bv;
    for (int k = 0; k < NDIM_; ++k) {
        float wv = Wn1l[k*HID_ + t];
        #pragma unroll
        for (int g = 0; g < 8; ++g) acc[g] += s_in[g][k] * wv;
    }
    #pragma unroll
    for (int g = 0; g < 8; ++g) s_u[g][t] = silu_(acc[g]);
    __syncthreads();
    if (t < FDIM_) {
        const float* Wn2l = Wn2 + l*HID_*FDIM_;
        float acc2[8];
        float b2v = bn2[l*FDIM_ + t];
        #pragma unroll
        for (int g = 0; g < 8; ++g) acc2[g] = b2v;
        for (int k = 0; k < HID_; ++k) {
            float wv = Wn2l[k*FDIM_ + t];
            #pragma unroll
            for (int g = 0; g < 8; ++g) acc2[g] += s_u[g][k] * wv;
        }
        #pragma unroll
        for (int g = 0; g < 8; ++g) {
            float nf = s_in[g][t] + acc2[g];
            feat_h[(node0 + g)*FS_ + t] = nf;
            s_in[g][t] = nf;                  // for W1 phase
        }
    } else if (t >= 96 && t < 120) {
        int idx = t - 96, g = idx / 3, d = idx % 3;
        int node = node0 + g;
        int bs = node / H_, h = node % H_;
        float xv = x[(bs*NN_ + h)*4 + d] + aggx[node*4 + d];
        x[(bs*NN_ + h)*4 + d] = xv;
        if (!do_w1) {                         // last layer: write output
            int b = bs / S_;
            out[node*3 + d] = (xv - x0h[node*4 + d]) * amask[b*H_ + h];
        }
    }
    if (!do_w1) return;
    __syncthreads();
    // ---- next-layer W1 projections for the 8 updated h nodes ----
    {
        const float* W1n = W1 + (l + 1)*EDIM_*HID_;
        float hia[8], hja[8];
        #pragma unroll
        for (int g = 0; g < 8; ++g) { hia[g] = 0.f; hja[g] = 0.f; }
        for (int f = 0; f < FDIM_; ++f) {
            float wi = W1n[f*HID_ + t];
            float wj = W1n[(FDIM_ + f)*HID_ + t];
            #pragma unroll
            for (int g = 0; g < 8; ++g) {
                float v = s_in[g][f];
                hia[g] += v * wi;
                hja[g] += v * wj;
            }
        }
        #pragma unroll
        for (int g = 0; g < 8; ++g) {
            hiW1[(size_t)(node0 + g)*HID_ + t] = hia[g];
            hjW1[(size_t)(node0 + g)*HID_ + t] = hja[g];
        }
    }
}

// ---------------- launch ----------------
extern "C" void kernel_launch(void* const* d_in, const int* in_sizes, int n_in,
                              void* d_out, int out_size, void* d_ws, size_t ws_size,
                              hipStream_t stream)
{
    const float* t_in  = (const float*)d_in[0];
    const float* x_h   = (const float*)d_in[1];
    const float* x_hv  = (const float*)d_in[2];
    const float* bond  = (const float*)d_in[3];
    const float* em_hv = (const float*)d_in[4];
    const float* em_hh = (const float*)d_in[5];
    const float* amask = (const float*)d_in[6];
    const float* W1    = (const float*)d_in[7];
    const float* b1    = (const float*)d_in[8];
    const float* W2    = (const float*)d_in[9];
    const float* b2    = (const float*)d_in[10];
    const float* Wc1   = (const float*)d_in[11];
    const float* bc1   = (const float*)d_in[12];
    const float* Wc2   = (const float*)d_in[13];
    const float* Wn1   = (const float*)d_in[14];
    const float* bn1   = (const float*)d_in[15];
    const float* Wn2   = (const float*)d_in[16];
    const float* bn2   = (const float*)d_in[17];
    const int* pep     = (const int*)d_in[18];
    const int* lab_hv  = (const int*)d_in[19];
    const int* lab_h   = (const int*)d_in[20];
    const int* pos_hv  = (const int*)d_in[21];
    const int* pos_h   = (const int*)d_in[22];
    const int* ehh     = (const int*)d_in[23];
    const int* bound   = (const int*)d_in[24];

    float* ws     = (float*)d_ws;
    float* feat_h = ws + OFF_FEATH;
    float* x      = ws + OFF_X;
    float* x0h    = ws + OFF_X0H;
    int*   erow   = (int*)(ws + OFF_EROW);
    int*   ecol   = (int*)(ws + OFF_ECOL);
    float* emk    = ws + OFF_EMASK;
    float* ebd    = ws + OFF_EBOND;
    float* hiW1   = ws + OFF_HIW1;
    float* hjW1   = ws + OFF_HJW1;
    unsigned short* Wp = (unsigned short*)(ws + OFF_WP);

    hipLaunchKernelGGL(k_setup, dim3(SETUP_BLKS_), dim3(256), 0, stream,
                       x_h, x_hv, bound, ehh, em_hh, em_hv, bond, W1, W2, Wc1,
                       lab_h, pos_h, lab_hv, pos_hv, pep,
                       feat_h, x, x0h, erow, ecol, emk, ebd,
                       hiW1, hjW1, ws + OFF_AGG0, Wp);

    for (int l = 0; l < L_; ++l) {
        float* aggx_l = ws + OFF_AGG0 + (size_t)l*AGGSTRIDE_;
        float* aggm_l = aggx_l + 6400;
        hipLaunchKernelGGL(k_edge_mlp, dim3(TOTE_/TE_), dim3(256), 0, stream,
                           x, hiW1, hjW1, erow, ecol, emk, ebd, t_in,
                           W1, b1, b2, bc1, Wc2, Wp, l, aggx_l, aggm_l);
        int do_w1 = (l == 0);
        float* zbase = ws + OFF_AGG0 + (size_t)(l + 1)*AGGSTRIDE_;  // unused when l==1
        hipLaunchKernelGGL(k_update, dim3(do_w1 ? 407 : 200), dim3(128), 0, stream,
                           feat_h, x, aggm_l, aggx_l, Wn1, bn1, Wn2, bn2, l,
                           W1, hiW1, hjW1,
                           do_w1 ? zbase : (ws + OFF_AGG0), do_w1,
                           x0h, amask, (float*)d_out);
    }
}

// Round 5
// 448.126 us; speedup vs baseline: 11.0665x; 1.0835x over previous
//
#include <hip/hip_runtime.h>
#include <math.h>

// Problem constants
#define B_     8
#define S_     4
#define H_     50
#define NH_    200
#define EHH_   400
#define L_     2
#define HID_   128
#define FDIM_  79          // 44 + 20 + 15
#define EDIM_  161         // 2*FDIM + 3
#define NN_    250         // H + NH
#define NE_    10400       // EHH + H*NH
#define BS_    32          // B*S
#define TOTE_  (BS_*NE_)   // 332800
#define FS_    80          // feat row stride
#define TE_    64          // edges per block in edge kernel
#define MSTR_  136         // s_m stride in bf16 (128 + 8)
#define NDIM_  207         // FDIM + HID

// Workspace layout (float offsets)
#define OFF_FEATH  0         // BS*H*80 = 128000
#define OFF_X      128000    // BS*NN*4 = 32000
#define OFF_X0H    160000    // BS*H*4  = 6400
#define OFF_EROW   166400    // 83200 (int)
#define OFF_ECOL   249600    // 83200 (int)
#define OFF_EMASK  332800    // 83200
#define OFF_EBOND  416000    // 83200
#define OFF_AGG0   499200    // aggx0(6400) + aggm0(204800) = 211200
#define OFF_AGG1   710400    // 211200
#define OFF_HIW1   921600    // fp32 1600*128 = 204800 (b1 + t*w160 folded in)
#define OFF_HJW1   1126400   // fp32 4800*128: [0,1600) h cur | [1600,3200) hv l0 | [3200,4800) hv l1
#define OFF_WP     1740800   // 65536 ushort = 32768 floats
#define AGGSTRIDE_ 211200

typedef __attribute__((ext_vector_type(8))) short short8;
typedef __attribute__((ext_vector_type(4))) float f32x4;

__device__ __forceinline__ float silu_(float v) {
    // hardware rcp instead of exact fp32 divide (saves ~9 VALU per call)
    return v * __builtin_amdgcn_rcpf(1.0f + __expf(-v));
}
__device__ __forceinline__ unsigned short f2bf(float f) {
    unsigned int u = __float_as_uint(f);
    unsigned int r = (u + 0x7fffu + ((u >> 16) & 1u)) >> 16;
    return (unsigned short)r;
}
__device__ __forceinline__ float bf2f(unsigned short v) {
    return __uint_as_float(((unsigned int)v) << 16);
}

// ================= fused setup =================
#define HV_BLKS_    1600   // heavy hjW1 both layers: 409600
#define PACK_BLKS_  256    // 65536
#define EDGE_BLKS_  325    // grid edges of 83200 (skip e<400)
#define SORT_BLKS_  8      // counting-sort hh edges by row, per b
#define HROW_BLKS_  200    // 400*128
#define FEAT_BLKS_  125    // 400*80
#define ZERO_BLKS_  207    // 52800 float4
#define XI_BLKS_    32     // 8000
#define SETUP_BLKS_ (HV_BLKS_ + PACK_BLKS_ + EDGE_BLKS_ + SORT_BLKS_ + HROW_BLKS_ + FEAT_BLKS_ + ZERO_BLKS_ + XI_BLKS_)

__global__ __launch_bounds__(256) void k_setup(
    const float* __restrict__ x_h, const float* __restrict__ x_hv,
    const int* __restrict__ bound,
    const int* __restrict__ ehh, const float* __restrict__ em_hh,
    const float* __restrict__ em_hv, const float* __restrict__ bond,
    const float* __restrict__ W1, const float* __restrict__ b1,
    const float* __restrict__ t_in,
    const float* __restrict__ W2, const float* __restrict__ Wc1,
    const int* __restrict__ lab_h, const int* __restrict__ pos_h,
    const int* __restrict__ lab_hv, const int* __restrict__ pos_hv,
    const int* __restrict__ pep,
    float* __restrict__ feat_h,
    float* __restrict__ x, float* __restrict__ x0h,
    int* __restrict__ erow, int* __restrict__ ecol,
    float* __restrict__ emk, float* __restrict__ ebd,
    float* __restrict__ hiW1, float* __restrict__ hjW1,
    float* __restrict__ agg0,
    unsigned short* __restrict__ Wp)
{
    int blk = blockIdx.x, t = threadIdx.x;
    if (blk < HV_BLKS_) {
        int g = blk*256 + t;                 // [0, 409600)
        int l = g / 204800;
        int r = g - l*204800;
        int node = r >> 7, col = r & 127;    // node = b*NH + nh
        int b = node / NH_;
        int label = lab_hv[node], pos = pos_hv[node];
        int aa = pep[b*15 + pos - 1];
        const float* W1l = W1 + l*EDIM_*HID_;
        float hj = W1l[(FDIM_ + label)*HID_ + col]
                 + W1l[(FDIM_ + 44 + aa)*HID_ + col]
                 + W1l[(FDIM_ + 64 + pos - 1)*HID_ + col];
        hjW1[(size_t)(1600 + l*1600 + node)*HID_ + col] = hj;
        return;
    }
    blk -= HV_BLKS_;
    if (blk < PACK_BLKS_) {
        int g = blk*256 + t;
        int idx = g & 16383;
        int lm  = g >> 14;
        int l = lm >> 1, mat = lm & 1;
        int j = idx & 7, q = (idx >> 3) & 3, n = (idx >> 5) & 127, kc = idx >> 12;
        int k = kc*32 + q*8 + j;
        const float* W = (mat == 0 ? W2 : Wc1) + l*HID_*HID_;
        Wp[g] = f2bf(W[k*HID_ + n]);
        return;
    }
    blk -= PACK_BLKS_;
    if (blk < EDGE_BLKS_) {
        int g = blk*256 + t;                  // [0, 83200)
        int b = g / NE_, e = g % NE_;
        if (e < EHH_) return;                 // hh edges handled by sort phase
        int k = e - EHH_;
        int r = k / NH_; int cc = k % NH_; int c = H_ + cc;
        erow[g] = r; ecol[g] = c;
        emk[g] = em_hv[(b*H_ + r)*NH_ + cc];
        ebd[g] = bond [(b*H_ + r)*NH_ + cc];
        return;
    }
    blk -= EDGE_BLKS_;
    if (blk < SORT_BLKS_) {
        // counting-sort the 400 hh edges of batch b by row -> long runs for agg
        int b = blk;
        __shared__ int scnt[64];
        __shared__ int srow[EHH_], scol[EHH_];
        __shared__ float sem[EHH_];
        if (t < 64) scnt[t] = 0;
        __syncthreads();
        for (int e = t; e < EHH_; e += 256) {
            int r = ehh[(b*EHH_ + e)*2 + 0];
            srow[e] = r;
            scol[e] = ehh[(b*EHH_ + e)*2 + 1];
            sem[e]  = em_hh[b*EHH_ + e];
            atomicAdd(&scnt[r], 1);
        }
        __syncthreads();
        if (t == 0) {
            int acc = 0;
            for (int i = 0; i < H_; ++i) { int v = scnt[i]; scnt[i] = acc; acc += v; }
        }
        __syncthreads();
        for (int e = t; e < EHH_; e += 256) {
            int r = srow[e];
            int pos = atomicAdd(&scnt[r], 1);
            int g = b*NE_ + pos;
            erow[g] = r; ecol[g] = scol[e]; emk[g] = sem[e]; ebd[g] = 0.0f;
        }
        return;
    }
    blk -= SORT_BLKS_;
    if (blk < HROW_BLKS_) {
        // h-node layer-0 projections; fold b1 and t*w160 into hiW1
        int g = blk*256 + t;                 // [0, 51200)
        int node = g >> 7, col = g & 127;    // node = b*H + h
        int b = node / H_;
        int label = lab_h[node], pos = pos_h[node];
        int aa = pep[b*15 + pos - 1];
        const float* W1l = W1;               // layer 0
        float hi = W1l[label*HID_ + col]
                 + W1l[(44 + aa)*HID_ + col]
                 + W1l[(64 + pos - 1)*HID_ + col]
                 + b1[col]
                 + t_in[b] * W1l[160*HID_ + col];
        float hj = W1l[(FDIM_ + label)*HID_ + col]
                 + W1l[(FDIM_ + 44 + aa)*HID_ + col]
                 + W1l[(FDIM_ + 64 + pos - 1)*HID_ + col];
        int h = node % H_;
        #pragma unroll
        for (int s = 0; s < S_; ++s) {
            int row = (b*S_ + s)*H_ + h;
            hiW1[(size_t)row*HID_ + col] = hi;
            hjW1[(size_t)row*HID_ + col] = hj;
        }
        return;
    }
    blk -= HROW_BLKS_;
    if (blk < FEAT_BLKS_) {
        int g = blk*256 + t;                 // [0, 32000)
        int node = g / FS_, f = g % FS_;     // node = b*H + h
        int b = node / H_, h = node % H_;
        int label = lab_h[node], pos = pos_h[node];
        int aa = pep[b*15 + pos - 1];
        float v = 0.f;
        if (f < 44)      v = (f == label)          ? 1.0f : 0.0f;
        else if (f < 64) v = ((f - 44) == aa)      ? 1.0f : 0.0f;
        else if (f < 79) v = ((f - 64) == pos - 1) ? 1.0f : 0.0f;
        #pragma unroll
        for (int s = 0; s < S_; ++s)
            feat_h[((b*S_ + s)*H_ + h)*FS_ + f] = v;
        return;
    }
    blk -= FEAT_BLKS_;
    if (blk < ZERO_BLKS_) {
        int idx = blk*256 + t;
        if (idx < 52800) ((float4*)agg0)[idx] = make_float4(0.f, 0.f, 0.f, 0.f);
        return;
    }
    blk -= ZERO_BLKS_;
    {
        int g = blk*256 + t;
        if (g >= BS_*NN_) return;
        int bs = g / NN_, n = g % NN_;
        int b = bs / S_;
        if (n < H_) {
            int ba = bound[b*H_ + n];
            for (int d = 0; d < 3; ++d) {
                float v = x_h[(bs*H_ + n)*3 + d] + x_hv[(b*NH_ + ba)*3 + d];
                x[g*4 + d] = v;
                x0h[(bs*H_ + n)*4 + d] = v;
            }
        } else {
            int nh = n - H_;
            for (int d = 0; d < 3; ++d) x[g*4 + d] = x_hv[(b*NH_ + nh)*3 + d];
        }
    }
}

// ============ per-layer: fused MFMA edge MLP + segment aggregation ============
__global__ __launch_bounds__(256, 4) void k_edge_mlp(
    const float* __restrict__ x, const float* __restrict__ hiW1,
    const float* __restrict__ hjW1,
    const int* __restrict__ erow, const int* __restrict__ ecol,
    const float* __restrict__ emk, const float* __restrict__ ebd,
    const float* __restrict__ W1,
    const float* __restrict__ b2, const float* __restrict__ bc1,
    const float* __restrict__ Wc2,
    const unsigned short* __restrict__ Wp, int l,
    float* __restrict__ aggx, float* __restrict__ aggm)
{
    __shared__ unsigned short s_m[TE_][MSTR_];   // 17408 B
    __shared__ float s_partT[16][68];            // 4352 B
    __shared__ float s_diff[TE_][4];
    __shared__ float s_db  [TE_][2];             // dist, bond
    __shared__ float s_emk [TE_];
    __shared__ float s_cw  [TE_];
    __shared__ int   s_ii  [TE_];                // bs*H + row
    __shared__ int   s_jj  [TE_];                // hjW1 row index

    const int t = threadIdx.x;
    const int lane = t & 63, w = t >> 6;
    const int l15 = lane & 15, q = lane >> 4;

    // ---- setup: per-edge scalars ----
    if (t < TE_) {
        int ge = blockIdx.x*TE_ + t;
        int bs = ge / NE_;
        int e  = ge - bs*NE_;
        int b  = bs / S_;
        int row = erow[b*NE_ + e], col = ecol[b*NE_ + e];
        s_ii[t] = bs*H_ + row;
        s_jj[t] = (col < H_) ? (bs*H_ + col) : (1600 + l*1600 + b*NH_ + (col - H_));
        float dx0 = x[(bs*NN_ + row)*4 + 0] - x[(bs*NN_ + col)*4 + 0];
        float dx1 = x[(bs*NN_ + row)*4 + 1] - x[(bs*NN_ + col)*4 + 1];
        float dx2 = x[(bs*NN_ + row)*4 + 2] - x[(bs*NN_ + col)*4 + 2];
        s_diff[t][0] = dx0; s_diff[t][1] = dx1; s_diff[t][2] = dx2;
        s_db[t][0] = sqrtf(dx0*dx0 + dx1*dx1 + dx2*dx2);
        s_db[t][1] = ebd[b*NE_ + e];
        s_emk[t]   = emk[b*NE_ + e];
    }
    __syncthreads();

    const int mrow = w*16 + l15;   // this lane's A-row (edge)

    // ---- stage 1 (register-direct): b1,t*w160 pre-folded into hiW1 ----
    short8 afrag[4];
    {
        const float* W1l = W1 + l*EDIM_*HID_;
        int ri = s_ii[mrow], rj = s_jj[mrow];
        float dist = s_db[mrow][0], bond = s_db[mrow][1];
        const float* pi = hiW1 + (size_t)ri*HID_ + q*8;
        const float* pj = hjW1 + (size_t)rj*HID_ + q*8;
        #pragma unroll
        for (int kc = 0; kc < 4; ++kc) {
            int k0 = kc*32 + q*8;
            float4 a0 = *(const float4*)(pi + kc*32);
            float4 a1 = *(const float4*)(pi + kc*32 + 4);
            float4 c0 = *(const float4*)(pj + kc*32);
            float4 c1 = *(const float4*)(pj + kc*32 + 4);
            float4 wa0 = *(const float4*)(W1l + 158*HID_ + k0);
            float4 wa1 = *(const float4*)(W1l + 158*HID_ + k0 + 4);
            float4 wb0 = *(const float4*)(W1l + 159*HID_ + k0);
            float4 wb1 = *(const float4*)(W1l + 159*HID_ + k0 + 4);
            short8 fr;
            fr[0] = (short)f2bf(silu_(a0.x + c0.x + dist*wa0.x + bond*wb0.x));
            fr[1] = (short)f2bf(silu_(a0.y + c0.y + dist*wa0.y + bond*wb0.y));
            fr[2] = (short)f2bf(silu_(a0.z + c0.z + dist*wa0.z + bond*wb0.z));
            fr[3] = (short)f2bf(silu_(a0.w + c0.w + dist*wa0.w + bond*wb0.w));
            fr[4] = (short)f2bf(silu_(a1.x + c1.x + dist*wa1.x + bond*wb1.x));
            fr[5] = (short)f2bf(silu_(a1.y + c1.y + dist*wa1.y + bond*wb1.y));
            fr[6] = (short)f2bf(silu_(a1.z + c1.z + dist*wa1.z + bond*wb1.z));
            fr[7] = (short)f2bf(silu_(a1.w + c1.w + dist*wa1.w + bond*wb1.w));
            afrag[kc] = fr;
        }
    }

    // ---- stage 2: m = silu(m1 @ W2 + b2) * emask  (bias in acc init) ----
    {
        const unsigned short* Wp2 = Wp + (size_t)(l*2 + 0)*16384;
        const float* b2l = b2 + l*HID_;
        float em4[4];
        #pragma unroll
        for (int r = 0; r < 4; ++r) em4[r] = s_emk[w*16 + q*4 + r];
        #pragma unroll
        for (int nt = 0; nt < 8; ++nt) {
            int colj = nt*16 + l15;
            float bias = b2l[colj];
            f32x4 c = {bias, bias, bias, bias};
            #pragma unroll
            for (int kc = 0; kc < 4; ++kc) {
                short8 bfrag = *(const short8*)&Wp2[((kc*128 + nt*16 + l15)*4 + q)*8];
                c = __builtin_amdgcn_mfma_f32_16x16x32_bf16(afrag[kc], bfrag, c, 0, 0, 0);
            }
            #pragma unroll
            for (int r = 0; r < 4; ++r)
                s_m[w*16 + q*4 + r][colj] = f2bf(silu_(c[r]) * em4[r]);
        }
    }
    __builtin_amdgcn_wave_barrier();   // wave-private rows: ds_write before ds_read

    // ---- stage 3: cw = silu(m @ Wc1 + bc1) @ Wc2 ----
    {
        short8 af2[4];
        #pragma unroll
        for (int kc = 0; kc < 4; ++kc)
            af2[kc] = *(const short8*)&s_m[mrow][kc*32 + q*8];
        const unsigned short* Wp3 = Wp + (size_t)(l*2 + 1)*16384;
        const float* bc1l = bc1 + l*HID_;
        const float* wc2l = Wc2 + l*HID_;
        float p[4] = {0.f, 0.f, 0.f, 0.f};
        #pragma unroll
        for (int nt = 0; nt < 8; ++nt) {
            int colj = nt*16 + l15;
            float bias = bc1l[colj];
            f32x4 c = {bias, bias, bias, bias};
            #pragma unroll
            for (int kc = 0; kc < 4; ++kc) {
                short8 bfrag = *(const short8*)&Wp3[((kc*128 + nt*16 + l15)*4 + q)*8];
                c = __builtin_amdgcn_mfma_f32_16x16x32_bf16(af2[kc], bfrag, c, 0, 0, 0);
            }
            float wcv = wc2l[colj];
            #pragma unroll
            for (int r = 0; r < 4; ++r)
                p[r] += silu_(c[r]) * wcv;
        }
        *(float4*)&s_partT[l15][w*16 + q*4] = make_float4(p[0], p[1], p[2], p[3]);
    }
    __syncthreads();

    // ---- cw reduce ----
    if (t < TE_) {
        float cwv = 0.f;
        #pragma unroll
        for (int c = 0; c < 16; ++c) cwv += s_partT[c][t];
        s_cw[t] = cwv;
    }
    __syncthreads();

    // ---- aggm: 256 threads, (col, half), 32-edge run-length scans ----
    {
        int j = t >> 1;
        int e0 = (t & 1) * 32;
        float run = 0.f; int ct = s_ii[e0];
        #pragma unroll 4
        for (int i2 = e0; i2 < e0 + 32; ++i2) {
            int tg = s_ii[i2];
            if (tg != ct) {
                atomicAdd(&aggm[(size_t)ct*HID_ + j], run);
                run = 0.f; ct = tg;
            }
            run += bf2f(s_m[i2][j]);
        }
        atomicAdd(&aggm[(size_t)ct*HID_ + j], run);
    }
    // ---- aggx: 12 threads of wave 3, (d, quarter), 16-edge scans ----
    if (t >= 192 && t < 204) {
        int idx = t - 192;
        int d = idx % 3, e0 = (idx / 3) * 16;
        float run = 0.f; int ct = s_ii[e0];
        for (int i2 = e0; i2 < e0 + 16; ++i2) {
            int tg = s_ii[i2];
            if (tg != ct) {
                atomicAdd(&aggx[(size_t)ct*4 + d], run);
                run = 0.f; ct = tg;
            }
            run += s_diff[i2][d] * s_cw[i2];
        }
        atomicAdd(&aggx[(size_t)ct*4 + d], run);
    }
}

// ====== per-layer: node update (8 nodes/block) + next-layer W1 (folded) + out ======
__global__ __launch_bounds__(128) void k_update(
    float* __restrict__ feat_h, float* __restrict__ x,
    const float* __restrict__ aggm, const float* __restrict__ aggx,
    const float* __restrict__ Wn1, const float* __restrict__ bn1,
    const float* __restrict__ Wn2, const float* __restrict__ bn2, int l,
    const float* __restrict__ W1, const float* __restrict__ b1,
    const float* __restrict__ t_in,
    float* __restrict__ hiW1, float* __restrict__ hjW1,
    float* __restrict__ zbase, int do_w1,
    const float* __restrict__ x0h, const float* __restrict__ amask,
    float* __restrict__ out)
{
    if (blockIdx.x >= 200) {
        int z = blockIdx.x - 200;
        for (int idx = z*128 + threadIdx.x; idx < 52800; idx += 207*128)
            ((float4*)zbase)[idx] = make_float4(0.f, 0.f, 0.f, 0.f);
        return;
    }
    __shared__ float s_in[8][NDIM_ + 1];
    __shared__ float s_u[8][HID_ + 1];
    int node0 = blockIdx.x * 8;            // bs*H + h
    int t = threadIdx.x;
    for (int idx = t; idx < 8*(NDIM_ + 1); idx += 128) {
        int g = idx / (NDIM_ + 1), k = idx % (NDIM_ + 1);
        float v = 0.f;
        if (k < FDIM_)      v = feat_h[(node0 + g)*FS_ + k];
        else if (k < NDIM_) v = aggm[(size_t)(node0 + g)*HID_ + (k - FDIM_)];
        s_in[g][k] = v;
    }
    __syncthreads();
    const float* Wn1l = Wn1 + l*NDIM_*HID_;
    float acc[8];
    float bv = bn1[l*HID_ + t];
    #pragma unroll
    for (int g = 0; g < 8; ++g) acc[g] = bv;
    for (int k = 0; k < NDIM_; ++k) {
        float wv = Wn1l[k*HID_ + t];
        #pragma unroll
        for (int g = 0; g < 8; ++g) acc[g] += s_in[g][k] * wv;
    }
    #pragma unroll
    for (int g = 0; g < 8; ++g) s_u[g][t] = silu_(acc[g]);
    __syncthreads();
    if (t < FDIM_) {
        const float* Wn2l = Wn2 + l*HID_*FDIM_;
        float acc2[8];
        float b2v = bn2[l*FDIM_ + t];
        #pragma unroll
        for (int g = 0; g < 8; ++g) acc2[g] = b2v;
        for (int k = 0; k < HID_; ++k) {
            float wv = Wn2l[k*FDIM_ + t];
            #pragma unroll
            for (int g = 0; g < 8; ++g) acc2[g] += s_u[g][k] * wv;
        }
        #pragma unroll
        for (int g = 0; g < 8; ++g) {
            float nf = s_in[g][t] + acc2[g];
            feat_h[(node0 + g)*FS_ + t] = nf;
            s_in[g][t] = nf;
        }
    } else if (t >= 96 && t < 120) {
        int idx = t - 96, g = idx / 3, d = idx % 3;
        int node = node0 + g;
        int bs = node / H_, h = node % H_;
        float xv = x[(bs*NN_ + h)*4 + d] + aggx[node*4 + d];
        x[(bs*NN_ + h)*4 + d] = xv;
        if (!do_w1) {
            int b = bs / S_;
            out[node*3 + d] = (xv - x0h[node*4 + d]) * amask[b*H_ + h];
        }
    }
    if (!do_w1) return;
    __syncthreads();
    // ---- next-layer W1 projections (fold b1 + t*w160 into hiW1) ----
    {
        const float* W1n = W1 + (l + 1)*EDIM_*HID_;
        float w160 = W1n[160*HID_ + t];
        float b1v  = b1[(l + 1)*HID_ + t];
        float hia[8], hja[8];
        #pragma unroll
        for (int g = 0; g < 8; ++g) { hia[g] = 0.f; hja[g] = 0.f; }
        for (int f = 0; f < FDIM_; ++f) {
            float wi = W1n[f*HID_ + t];
            float wj = W1n[(FDIM_ + f)*HID_ + t];
            #pragma unroll
            for (int g = 0; g < 8; ++g) {
                float v = s_in[g][f];
                hia[g] += v * wi;
                hja[g] += v * wj;
            }
        }
        #pragma unroll
        for (int g = 0; g < 8; ++g) {
            int node = node0 + g;
            int b = (node / H_) / S_;
            hiW1[(size_t)node*HID_ + t] = hia[g] + b1v + t_in[b]*w160;
            hjW1[(size_t)node*HID_ + t] = hja[g];
        }
    }
}

// ---------------- launch ----------------
extern "C" void kernel_launch(void* const* d_in, const int* in_sizes, int n_in,
                              void* d_out, int out_size, void* d_ws, size_t ws_size,
                              hipStream_t stream)
{
    const float* t_in  = (const float*)d_in[0];
    const float* x_h   = (const float*)d_in[1];
    const float* x_hv  = (const float*)d_in[2];
    const float* bond  = (const float*)d_in[3];
    const float* em_hv = (const float*)d_in[4];
    const float* em_hh = (const float*)d_in[5];
    const float* amask = (const float*)d_in[6];
    const float* W1    = (const float*)d_in[7];
    const float* b1    = (const float*)d_in[8];
    const float* W2    = (const float*)d_in[9];
    const float* b2    = (const float*)d_in[10];
    const float* Wc1   = (const float*)d_in[11];
    const float* bc1   = (const float*)d_in[12];
    const float* Wc2   = (const float*)d_in[13];
    const float* Wn1   = (const float*)d_in[14];
    const float* bn1   = (const float*)d_in[15];
    const float* Wn2   = (const float*)d_in[16];
    const float* bn2   = (const float*)d_in[17];
    const int* pep     = (const int*)d_in[18];
    const int* lab_hv  = (const int*)d_in[19];
    const int* lab_h   = (const int*)d_in[20];
    const int* pos_hv  = (const int*)d_in[21];
    const int* pos_h   = (const int*)d_in[22];
    const int* ehh     = (const int*)d_in[23];
    const int* bound   = (const int*)d_in[24];

    float* ws     = (float*)d_ws;
    float* feat_h = ws + OFF_FEATH;
    float* x      = ws + OFF_X;
    float* x0h    = ws + OFF_X0H;
    int*   erow   = (int*)(ws + OFF_EROW);
    int*   ecol   = (int*)(ws + OFF_ECOL);
    float* emk    = ws + OFF_EMASK;
    float* ebd    = ws + OFF_EBOND;
    float* hiW1   = ws + OFF_HIW1;
    float* hjW1   = ws + OFF_HJW1;
    unsigned short* Wp = (unsigned short*)(ws + OFF_WP);

    hipLaunchKernelGGL(k_setup, dim3(SETUP_BLKS_), dim3(256), 0, stream,
                       x_h, x_hv, bound, ehh, em_hh, em_hv, bond,
                       W1, b1, t_in, W2, Wc1,
                       lab_h, pos_h, lab_hv, pos_hv, pep,
                       feat_h, x, x0h, erow, ecol, emk, ebd,
                       hiW1, hjW1, ws + OFF_AGG0, Wp);

    for (int l = 0; l < L_; ++l) {
        float* aggx_l = ws + OFF_AGG0 + (size_t)l*AGGSTRIDE_;
        float* aggm_l = aggx_l + 6400;
        hipLaunchKernelGGL(k_edge_mlp, dim3(TOTE_/TE_), dim3(256), 0, stream,
                           x, hiW1, hjW1, erow, ecol, emk, ebd,
                           W1, b2, bc1, Wc2, Wp, l, aggx_l, aggm_l);
        int do_w1 = (l == 0);
        float* zbase = ws + OFF_AGG0 + (size_t)(l + 1)*AGGSTRIDE_;
        hipLaunchKernelGGL(k_update, dim3(do_w1 ? 407 : 200), dim3(128), 0, stream,
                           feat_h, x, aggm_l, aggx_l, Wn1, bn1, Wn2, bn2, l,
                           W1, b1, t_in, hiW1, hjW1,
                           do_w1 ? zbase : (ws + OFF_AGG0), do_w1,
                           x0h, amask, (float*)d_out);
    }
}